// Round 17
// baseline (507.142 us; speedup 1.0000x reference)
//
#include <hip/hip_runtime.h>
#include <hip/hip_bf16.h>
#include <stdint.h>

typedef __bf16 bf16x8 __attribute__((ext_vector_type(8)));
typedef float f32x4 __attribute__((ext_vector_type(4)));
typedef float f32x16 __attribute__((ext_vector_type(16)));
typedef unsigned short ushort_t;
typedef ushort_t ushort4v __attribute__((ext_vector_type(4)));
typedef ushort_t ushort8v __attribute__((ext_vector_type(8)));
typedef float float4v __attribute__((ext_vector_type(4)));
typedef uint32_t u32x4 __attribute__((ext_vector_type(4)));

#define D_MODEL 2048
#define NH 16
#define HD 128
#define B_ 4
#define T_ 2048
#define M_ (B_*T_)

__device__ __forceinline__ float b2f(ushort_t u){ union{uint32_t i; float f;} v; v.i=((uint32_t)u)<<16; return v.f; }
__device__ __forceinline__ ushort_t f2b(float f){ union{float f; uint32_t i;} v; v.f=f; uint32_t r = v.i + 0x7FFFu + ((v.i>>16)&1u); return (ushort_t)(r>>16); }
__device__ __forceinline__ float fexp2(float x){ return __builtin_amdgcn_exp2f(x); }
__device__ __forceinline__ uint32_t cvtpk(float lo, float hi){
  uint32_t r; asm("v_cvt_pk_bf16_f32 %0, %1, %2" : "=v"(r) : "v"(lo), "v"(hi)); return r;
}
__device__ __forceinline__ uint32_t lswap(uint32_t x){
  asm volatile("v_permlane32_swap_b32 %0, %0" : "+v"(x)); return x;
}

__device__ __forceinline__ void gload16(const void* g, void* l) {
  __builtin_amdgcn_global_load_lds((const __attribute__((address_space(1))) void*)g,
                                   (__attribute__((address_space(3))) void*)l, 16, 0, 0);
}

// ---------------- fused prelude: convert x, transpose W_attn, transpose W_proj, RoPE tables ---
__global__ void prelude_kernel(const float* __restrict__ x, ushort_t* __restrict__ xb,
                               const float* __restrict__ W_attn, ushort_t* __restrict__ Wa,
                               const float* __restrict__ W_proj, ushort_t* __restrict__ Wp,
                               float* __restrict__ cosT, float* __restrict__ sinT) {
  __shared__ float tile[32][33];
  const int b = blockIdx.x, tid = threadIdx.x;
  if (b < 16384) {
    int idx = b*256 + tid;
    float4v v = *reinterpret_cast<const float4v*>(x + (size_t)idx*4);
    ushort4v r;
    #pragma unroll
    for (int e=0;e<4;e++) r[e]=f2b(v[e]);
    *reinterpret_cast<ushort4v*>(xb + (size_t)idx*4) = r;
  } else if (b < 16384 + 12288 + 4096) {
    const bool isA = (b < 16384 + 12288);
    const int r = isA ? (b - 16384) : (b - 16384 - 12288);
    const int NW = isA ? 3*D_MODEL : D_MODEL;
    const int nt = isA ? (r % 192) : (r % 64);
    const int kt = isA ? (r / 192) : (r / 64);
    const float* W = isA ? W_attn : W_proj;
    ushort_t* Wt = isA ? Wa : Wp;
    const int xq = tid & 31, yq = tid >> 5;
    #pragma unroll
    for (int i=0;i<4;i++) {
      int k = kt*32 + yq + i*8;
      tile[yq+i*8][xq] = W[(size_t)k*NW + nt*32 + xq];
    }
    __syncthreads();
    #pragma unroll
    for (int i=0;i<4;i++) {
      int n = nt*32 + yq + i*8;
      Wt[(size_t)n*D_MODEL + kt*32 + xq] = f2b(tile[xq][yq+i*8]);
    }
  } else {
    int idx = (b - 16384 - 12288 - 4096)*256 + tid;
    int t = idx >> 6, i = idx & 63;
    float f = powf(10000.0f, -(float)(2*i)/128.0f);
    float ang = (float)t * f;
    cosT[idx] = cosf(ang);
    sinT[idx] = sinf(ang);
  }
}

// ---------------- GEMM: 128x128 tile, BK=64, 4 waves (proven structure) ----------------
// NOTE: no XCD swizzle (R10); no 256²/4-phase (R5/R6/R13 regressed vs this).
template<int EPI>
__global__ __launch_bounds__(256, 2)
void gemm_kernel(const ushort_t* __restrict__ A, const ushort_t* __restrict__ Bt,
                 const float* __restrict__ bias, float* __restrict__ Cf,
                 ushort_t* __restrict__ Qb, ushort_t* __restrict__ Kb, ushort_t* __restrict__ Vb,
                 const float* __restrict__ cosT, const float* __restrict__ sinT,
                 int M, int N, int K) {
  __shared__ __align__(16) ushort_t As[2][128*64];
  __shared__ __align__(16) ushort_t Bs[2][128*64];
  const int tid = threadIdx.x, lane = tid & 63, wid = tid >> 6;
  const int bm = blockIdx.x, bn = blockIdx.y;
  const int nt = K >> 6;
  constexpr int MF = (EPI==2) ? 2 : 4;
  constexpr int NF = (EPI==2) ? 8 : 4;
  const int rbase_w = (EPI==2) ? wid*32 : (wid>>1)*64;
  const int cbase_w = (EPI==2) ? 0      : (wid&1)*64;

  f32x4 acc[MF][NF];
  #pragma unroll
  for (int m=0;m<MF;m++)
    #pragma unroll
    for (int n=0;n<NF;n++) { f32x4 z = {0.f,0.f,0.f,0.f}; acc[m][n] = z; }

  const ushort_t* Abase = A + (size_t)(bm*128)*K;
  const ushort_t* Bbase = Bt + (size_t)(bn*128)*K;

  auto stage = [&](int buf, int kt) {
    const int rsub = (lane>>3);
    const int g = lane & 7;
    #pragma unroll
    for (int i=0;i<4;i++) {
      int chunk = wid*4 + i;
      int row = chunk*8 + rsub;
      int gl = g ^ (row & 7);
      gload16(Abase + (size_t)row*K + kt*64 + gl*8, &As[buf][chunk*512 + lane*8]);
      gload16(Bbase + (size_t)row*K + kt*64 + gl*8, &Bs[buf][chunk*512 + lane*8]);
    }
  };

  stage(0, 0);
  __syncthreads();

  for (int kt=0; kt<nt; ++kt) {
    int cur = kt & 1;
    if (kt+1 < nt) stage(cur^1, kt+1);
    #pragma unroll
    for (int ks=0; ks<2; ++ks) {
      bf16x8 a[MF], b[NF];
      #pragma unroll
      for (int m=0;m<MF;m++) {
        int r = rbase_w + m*16 + (lane&15);
        int gr = (ks*4 + (lane>>4)) ^ (r&7);
        a[m] = *reinterpret_cast<const bf16x8*>(&As[cur][r*64 + gr*8]);
      }
      #pragma unroll
      for (int n=0;n<NF;n++) {
        int r = cbase_w + n*16 + (lane&15);
        int gr = (ks*4 + (lane>>4)) ^ (r&7);
        b[n] = *reinterpret_cast<const bf16x8*>(&Bs[cur][r*64 + gr*8]);
      }
      #pragma unroll
      for (int m=0;m<MF;m++)
        #pragma unroll
        for (int n=0;n<NF;n++)
          acc[m][n] = __builtin_amdgcn_mfma_f32_16x16x32_bf16(a[m], b[n], acc[m][n], 0,0,0);
    }
    __syncthreads();
  }

  if (EPI == 1) {
    #pragma unroll
    for (int m=0;m<MF;m++)
      #pragma unroll
      for (int j=0;j<4;j++) {
        int row = bm*128 + rbase_w + m*16 + (lane>>4)*4 + j;
        #pragma unroll
        for (int n=0;n<NF;n++) {
          int col = bn*128 + cbase_w + n*16 + (lane&15);
          Cf[(size_t)row*N + col] = acc[m][n][j] + bias[col];
        }
      }
  } else {
    const int which = bn >> 4;                // 0=Q, 1=K, 2=V
    const int h = bn & 15;
    if (which < 2) {
      ushort_t* dst = (which==0) ? Qb : Kb;
      #pragma unroll
      for (int m=0;m<MF;m++)
        #pragma unroll
        for (int j=0;j<4;j++) {
          int t = bm*128 + rbase_w + m*16 + (lane>>4)*4 + j;
          int tt = t & (T_-1), bb = t >> 11;
          ushort_t* ptr = dst + ((size_t)(bb*NH + h)*T_ + tt)*HD;
          const float* cb = cosT + tt*64;
          const float* sb = sinT + tt*64;
          #pragma unroll
          for (int n=0;n<4;n++) {
            int d = n*16 + (lane&15);
            float x1 = acc[m][n][j]   + bias[bn*128 + d];
            float x2 = acc[m][n+4][j] + bias[bn*128 + d + 64];
            float cd = cb[d], sd = sb[d];
            ptr[d]    = f2b(x1*cd - x2*sd);
            ptr[d+64] = f2b(x2*cd + x1*sd);
          }
        }
    } else {
      ushort_t* sc = &As[0][0];
      #pragma unroll
      for (int m=0;m<MF;m++)
        #pragma unroll
        for (int j=0;j<4;j++) {
          int r = rbase_w + m*16 + (lane>>4)*4 + j;
          #pragma unroll
          for (int n=0;n<NF;n++) {
            int c = n*16 + (lane&15);
            float v = acc[m][n][j] + bias[bn*128 + c];
            sc[c*128 + (((r>>3)^(c&15))<<3) + (r&7)] = f2b(v);
          }
        }
      __syncthreads();
      int dr = tid >> 1, th = tid & 1;
      int bb = bm >> 4;
      int t0 = (bm & 15)*128 + th*64;
      ushort_t* dstp = Vb + ((size_t)(bb*NH + h)*HD + dr)*T_ + t0;
      #pragma unroll
      for (int k=0;k<8;k++) {
        ushort8v u = *reinterpret_cast<const ushort8v*>(&sc[dr*128 + (((th*8+k)^(dr&15))<<3)]);
        *reinterpret_cast<ushort8v*>(dstp + k*8) = u;
      }
    }
  }
}

// ---------------- flash attention (32x32 core, in-register P, QBLK=256 / 8 waves) --------
// Q,K [BH][T][D]; Vt [BH][D][T]; Y [B,T,C] bf16. 512 threads, wave owns 32 q-rows;
// staged K/V tile feeds 256 q-rows (staging + barriers per q-row halved vs QBLK=128).
// __launch_bounds__(512,2) keeps the 256-VGPR budget (R8 lesson: never cap below body needs).
__global__ __launch_bounds__(512, 2)
void attn_kernel(const ushort_t* __restrict__ Q, const ushort_t* __restrict__ K,
                 const ushort_t* __restrict__ Vt, ushort_t* __restrict__ Y) {
  __shared__ __align__(16) ushort_t Ks[2][64*128];
  __shared__ __align__(16) ushort_t Vs[2][64*128];
  const int tid = threadIdx.x, lane = tid & 63, w = tid >> 6;   // w in 0..7
  const int ql = lane & 31, hh = lane >> 5;
  const int qtb = (int)gridDim.x - 1 - (int)blockIdx.x;   // heavy blocks first
  const int bh = blockIdx.y;
  const size_t base = (size_t)bh * T_ * HD;
  const int NT = 4*qtb + 4;
  const int qmin = qtb*256 + w*32;
  const int qrow = qmin + ql;

  auto stage = [&](int buf, int kvt) {
    #pragma unroll
    for (int i=0;i<2;i++) {
      int c = i*512 + tid;            // 1024 chunks of 16B (K tile)
      int row = c >> 4, sl = c & 15;
      int g = sl ^ (row & 15);
      gload16(K + base + (size_t)(kvt*64 + row)*HD + g*8, &Ks[buf][c*8]);
    }
    #pragma unroll
    for (int i=0;i<2;i++) {
      int c = i*512 + tid;
      int j = c >> 4, sl = c & 15;
      int g = sl ^ (j & 15);
      int d = 2*j + (g >> 3);
      gload16(Vt + base + (size_t)d*T_ + kvt*64 + (g&7)*8, &Vs[buf][c*8]);
    }
  };

  stage(0, 0);

  bf16x8 qf[8];
  {
    const ushort_t* qp = Q + base + (size_t)qrow*HD + hh*8;
    #pragma unroll
    for (int kb=0; kb<8; ++kb) qf[kb] = *reinterpret_cast<const bf16x8*>(qp + kb*16);
  }

  f32x16 o[4];
  #pragma unroll
  for (int nv=0;nv<4;nv++)
    #pragma unroll
    for (int r=0;r<16;r++) o[nv][r] = 0.f;
  float mi = -1e30f, li = 0.f;
  const float C_ = 0.088388347648318447f * 1.4426950408889634f;
  const float THR = 8.0f / (0.088388347648318447f * 1.4426950408889634f);

  for (int kvt=0; kvt<NT; ++kvt) {
    int cur = kvt & 1;
    if (kvt+1 < NT) {
      stage(cur^1, kvt+1);
      asm volatile("s_waitcnt vmcnt(4)" ::: "memory");   // tile kvt's 4 loads landed
    } else {
      asm volatile("s_waitcnt vmcnt(0)" ::: "memory");
    }
    __builtin_amdgcn_sched_barrier(0);
    __builtin_amdgcn_s_barrier();
    __builtin_amdgcn_sched_barrier(0);

    bool active = (kvt*64 <= qmin + 31);   // wave-uniform
    if (active) {
      f32x16 s0, s1;
      #pragma unroll
      for (int r=0;r<16;r++) { s0[r] = 0.f; s1[r] = 0.f; }
      __builtin_amdgcn_s_setprio(1);
      #pragma unroll
      for (int kb=0;kb<8;kb++) {
        int gl = (kb*2 + hh) ^ (ql & 15);
        bf16x8 kf0 = *reinterpret_cast<const bf16x8*>(&Ks[cur][ql*128 + gl*8]);
        s0 = __builtin_amdgcn_mfma_f32_32x32x16_bf16(kf0, qf[kb], s0, 0,0,0);
        bf16x8 kf1 = *reinterpret_cast<const bf16x8*>(&Ks[cur][(32+ql)*128 + gl*8]);
        s1 = __builtin_amdgcn_mfma_f32_32x32x16_bf16(kf1, qf[kb], s1, 0,0,0);
      }
      __builtin_amdgcn_s_setprio(0);
      bool diag = (kvt*64 + 63 > qmin);
      if (diag) {
        #pragma unroll
        for (int r=0;r<16;r++) {
          int kv0 = kvt*64 + (r&3) + 8*(r>>2) + 4*hh;
          if (kv0 > qrow)      s0[r] = -1e30f;
          if (kv0 + 32 > qrow) s1[r] = -1e30f;
        }
      }
      float pm = fmaxf(s0[0], s1[0]);
      #pragma unroll
      for (int r=1;r<16;r++) pm = fmaxf(pm, fmaxf(s0[r], s1[r]));
      pm = fmaxf(pm, __shfl_xor(pm, 32));
      if (__any(pm > mi + THR)) {
        float mn = fmaxf(mi, pm);
        float alpha = fexp2((mi - mn)*C_);
        mi = mn;
        li *= alpha;
        #pragma unroll
        for (int nv=0;nv<4;nv++)
          #pragma unroll
          for (int r=0;r<16;r++) o[nv][r] *= alpha;
      }
      float p0[16], p1[16];
      #pragma unroll
      for (int r=0;r<16;r++) {
        p0[r] = fexp2((s0[r] - mi)*C_);
        p1[r] = fexp2((s1[r] - mi)*C_);
      }
      float rs = p0[0] + p1[0];
      #pragma unroll
      for (int r=1;r<16;r++) rs += p0[r] + p1[r];
      rs += __shfl_xor(rs, 32);
      li += rs;
      // PV: per-ks2 in-register P fragment (cvt_pk + self-permlane swap + cndmask)
      __builtin_amdgcn_s_setprio(1);
      #pragma unroll
      for (int ks2=0; ks2<4; ++ks2) {
        const int b8 = (ks2&1)*8;
        uint32_t c0 = (ks2<2) ? cvtpk(p0[b8+0], p0[b8+1]) : cvtpk(p1[b8+0], p1[b8+1]);
        uint32_t c1 = (ks2<2) ? cvtpk(p0[b8+2], p0[b8+3]) : cvtpk(p1[b8+2], p1[b8+3]);
        uint32_t c2 = (ks2<2) ? cvtpk(p0[b8+4], p0[b8+5]) : cvtpk(p1[b8+4], p1[b8+5]);
        uint32_t c3 = (ks2<2) ? cvtpk(p0[b8+6], p0[b8+7]) : cvtpk(p1[b8+6], p1[b8+7]);
        uint32_t sw0 = lswap(hh ? c0 : c2);
        uint32_t sw1 = lswap(hh ? c1 : c3);
        u32x4 pw;
        pw[0] = hh ? sw0 : c0;
        pw[1] = hh ? sw1 : c1;
        pw[2] = hh ? c2 : sw0;
        pw[3] = hh ? c3 : sw1;
        bf16x8 pa = __builtin_bit_cast(bf16x8, pw);
        #pragma unroll
        for (int nv=0; nv<4; ++nv) {
          int gv = ((ql&1)*8 + ks2*2 + hh) ^ (ql>>1);
          bf16x8 vf = *reinterpret_cast<const bf16x8*>(&Vs[cur][(nv*16 + (ql>>1))*128 + gv*8]);
          o[nv] = __builtin_amdgcn_mfma_f32_32x32x16_bf16(vf, pa, o[nv], 0,0,0);
        }
      }
      __builtin_amdgcn_s_setprio(0);
    }
    __builtin_amdgcn_s_barrier();
    __builtin_amdgcn_sched_barrier(0);
  }

  int bb = bh >> 4, hd = bh & 15;
  float inv = 1.0f / li;
  size_t rowbase = ((size_t)(bb*T_ + qrow))*D_MODEL + hd*HD;
  #pragma unroll
  for (int nv=0;nv<4;nv++) {
    #pragma unroll
    for (int qd=0;qd<4;qd++) {
      ushort4v r;
      #pragma unroll
      for (int i=0;i<4;i++) r[i] = f2b(o[nv][qd*4+i] * inv);
      *reinterpret_cast<ushort4v*>(&Y[rowbase + nv*32 + 8*qd + 4*hh]) = r;
    }
  }
}

extern "C" void kernel_launch(void* const* d_in, const int* in_sizes, int n_in,
                              void* d_out, int out_size, void* d_ws, size_t ws_size,
                              hipStream_t stream) {
  const float* x      = (const float*)d_in[0];
  const float* W_attn = (const float*)d_in[1];
  const float* b_attn = (const float*)d_in[2];
  const float* W_proj = (const float*)d_in[3];
  const float* b_proj = (const float*)d_in[4];
  float* out = (float*)d_out;

  char* ws = (char*)d_ws;
  size_t off = 0;
  ushort_t* xb = (ushort_t*)(ws + off); off += (size_t)M_*D_MODEL*2;        // 33.5MB
  ushort_t* Wa = (ushort_t*)(ws + off); off += (size_t)3*D_MODEL*D_MODEL*2; // 25.2MB
  ushort_t* Wp = (ushort_t*)(ws + off); off += (size_t)D_MODEL*D_MODEL*2;   // 8.4MB
  ushort_t* Qb = (ushort_t*)(ws + off); off += (size_t)M_*D_MODEL*2;        // 33.5MB
  ushort_t* Kb = (ushort_t*)(ws + off); off += (size_t)M_*D_MODEL*2;        // 33.5MB
  ushort_t* Vtg= (ushort_t*)(ws + off); off += (size_t)M_*D_MODEL*2;        // 33.5MB
  float* cosT = (float*)(ws + off); off += (size_t)T_*64*4;                 // 0.5MB
  float* sinT = (float*)(ws + off); off += (size_t)T_*64*4;                 // 0.5MB
  ushort_t* Yatt = xb;  // alias: xb dead after GEMM1

  prelude_kernel<<<16384 + 12288 + 4096 + 512, 256, 0, stream>>>(
      x, xb, W_attn, Wa, W_proj, Wp, cosT, sinT);

  gemm_kernel<2><<<dim3(64,48), 256, 0, stream>>>(xb, Wa, b_attn, nullptr,
                                                  Qb, Kb, Vtg, cosT, sinT, M_, 3*D_MODEL, D_MODEL);
  attn_kernel<<<dim3(8,64), 512, 0, stream>>>(Qb, Kb, Vtg, Yatt);
  gemm_kernel<1><<<dim3(64,16), 256, 0, stream>>>(Yatt, Wp, b_proj, out,
                                                  nullptr, nullptr, nullptr, nullptr, nullptr,
                                                  M_, D_MODEL, D_MODEL);
}

// Round 18
// 499.772 us; speedup vs baseline: 1.0147x; 1.0147x over previous
//
#include <hip/hip_runtime.h>
#include <hip/hip_bf16.h>
#include <stdint.h>

typedef __bf16 bf16x8 __attribute__((ext_vector_type(8)));
typedef float f32x4 __attribute__((ext_vector_type(4)));
typedef float f32x16 __attribute__((ext_vector_type(16)));
typedef unsigned short ushort_t;
typedef ushort_t ushort4v __attribute__((ext_vector_type(4)));
typedef ushort_t ushort8v __attribute__((ext_vector_type(8)));
typedef float float4v __attribute__((ext_vector_type(4)));
typedef uint32_t u32x4 __attribute__((ext_vector_type(4)));

#define D_MODEL 2048
#define NH 16
#define HD 128
#define B_ 4
#define T_ 2048
#define M_ (B_*T_)

__device__ __forceinline__ float b2f(ushort_t u){ union{uint32_t i; float f;} v; v.i=((uint32_t)u)<<16; return v.f; }
__device__ __forceinline__ ushort_t f2b(float f){ union{float f; uint32_t i;} v; v.f=f; uint32_t r = v.i + 0x7FFFu + ((v.i>>16)&1u); return (ushort_t)(r>>16); }
__device__ __forceinline__ float fexp2(float x){ return __builtin_amdgcn_exp2f(x); }
__device__ __forceinline__ uint32_t cvtpk(float lo, float hi){
  uint32_t r; asm("v_cvt_pk_bf16_f32 %0, %1, %2" : "=v"(r) : "v"(lo), "v"(hi)); return r;
}
__device__ __forceinline__ uint32_t lswap(uint32_t x){
  asm volatile("v_permlane32_swap_b32 %0, %0" : "+v"(x)); return x;
}

__device__ __forceinline__ void gload16(const void* g, void* l) {
  __builtin_amdgcn_global_load_lds((const __attribute__((address_space(1))) void*)g,
                                   (__attribute__((address_space(3))) void*)l, 16, 0, 0);
}

// ---------------- fused prelude: convert x, transpose W_attn, transpose W_proj, RoPE tables ---
__global__ void prelude_kernel(const float* __restrict__ x, ushort_t* __restrict__ xb,
                               const float* __restrict__ W_attn, ushort_t* __restrict__ Wa,
                               const float* __restrict__ W_proj, ushort_t* __restrict__ Wp,
                               float* __restrict__ cosT, float* __restrict__ sinT) {
  __shared__ float tile[32][33];
  const int b = blockIdx.x, tid = threadIdx.x;
  if (b < 16384) {
    int idx = b*256 + tid;
    float4v v = *reinterpret_cast<const float4v*>(x + (size_t)idx*4);
    ushort4v r;
    #pragma unroll
    for (int e=0;e<4;e++) r[e]=f2b(v[e]);
    *reinterpret_cast<ushort4v*>(xb + (size_t)idx*4) = r;
  } else if (b < 16384 + 12288 + 4096) {
    const bool isA = (b < 16384 + 12288);
    const int r = isA ? (b - 16384) : (b - 16384 - 12288);
    const int NW = isA ? 3*D_MODEL : D_MODEL;
    const int nt = isA ? (r % 192) : (r % 64);
    const int kt = isA ? (r / 192) : (r / 64);
    const float* W = isA ? W_attn : W_proj;
    ushort_t* Wt = isA ? Wa : Wp;
    const int xq = tid & 31, yq = tid >> 5;
    #pragma unroll
    for (int i=0;i<4;i++) {
      int k = kt*32 + yq + i*8;
      tile[yq+i*8][xq] = W[(size_t)k*NW + nt*32 + xq];
    }
    __syncthreads();
    #pragma unroll
    for (int i=0;i<4;i++) {
      int n = nt*32 + yq + i*8;
      Wt[(size_t)n*D_MODEL + kt*32 + xq] = f2b(tile[xq][yq+i*8]);
    }
  } else {
    int idx = (b - 16384 - 12288 - 4096)*256 + tid;
    int t = idx >> 6, i = idx & 63;
    float f = powf(10000.0f, -(float)(2*i)/128.0f);
    float ang = (float)t * f;
    cosT[idx] = cosf(ang);
    sinT[idx] = sinf(ang);
  }
}

// ---------------- GEMM: 128x128 tile, BK=64, 4 waves (proven structure) ----------------
// NOTE: no XCD swizzle (R10); no 256²/4-phase (R5/R6/R13 regressed vs this).
template<int EPI>
__global__ __launch_bounds__(256, 2)
void gemm_kernel(const ushort_t* __restrict__ A, const ushort_t* __restrict__ Bt,
                 const float* __restrict__ bias, float* __restrict__ Cf,
                 ushort_t* __restrict__ Qb, ushort_t* __restrict__ Kb, ushort_t* __restrict__ Vb,
                 const float* __restrict__ cosT, const float* __restrict__ sinT,
                 int M, int N, int K) {
  __shared__ __align__(16) ushort_t As[2][128*64];
  __shared__ __align__(16) ushort_t Bs[2][128*64];
  const int tid = threadIdx.x, lane = tid & 63, wid = tid >> 6;
  const int bm = blockIdx.x, bn = blockIdx.y;
  const int nt = K >> 6;
  constexpr int MF = (EPI==2) ? 2 : 4;
  constexpr int NF = (EPI==2) ? 8 : 4;
  const int rbase_w = (EPI==2) ? wid*32 : (wid>>1)*64;
  const int cbase_w = (EPI==2) ? 0      : (wid&1)*64;

  f32x4 acc[MF][NF];
  #pragma unroll
  for (int m=0;m<MF;m++)
    #pragma unroll
    for (int n=0;n<NF;n++) { f32x4 z = {0.f,0.f,0.f,0.f}; acc[m][n] = z; }

  const ushort_t* Abase = A + (size_t)(bm*128)*K;
  const ushort_t* Bbase = Bt + (size_t)(bn*128)*K;

  auto stage = [&](int buf, int kt) {
    const int rsub = (lane>>3);
    const int g = lane & 7;
    #pragma unroll
    for (int i=0;i<4;i++) {
      int chunk = wid*4 + i;
      int row = chunk*8 + rsub;
      int gl = g ^ (row & 7);
      gload16(Abase + (size_t)row*K + kt*64 + gl*8, &As[buf][chunk*512 + lane*8]);
      gload16(Bbase + (size_t)row*K + kt*64 + gl*8, &Bs[buf][chunk*512 + lane*8]);
    }
  };

  stage(0, 0);
  __syncthreads();

  for (int kt=0; kt<nt; ++kt) {
    int cur = kt & 1;
    if (kt+1 < nt) stage(cur^1, kt+1);
    #pragma unroll
    for (int ks=0; ks<2; ++ks) {
      bf16x8 a[MF], b[NF];
      #pragma unroll
      for (int m=0;m<MF;m++) {
        int r = rbase_w + m*16 + (lane&15);
        int gr = (ks*4 + (lane>>4)) ^ (r&7);
        a[m] = *reinterpret_cast<const bf16x8*>(&As[cur][r*64 + gr*8]);
      }
      #pragma unroll
      for (int n=0;n<NF;n++) {
        int r = cbase_w + n*16 + (lane&15);
        int gr = (ks*4 + (lane>>4)) ^ (r&7);
        b[n] = *reinterpret_cast<const bf16x8*>(&Bs[cur][r*64 + gr*8]);
      }
      #pragma unroll
      for (int m=0;m<MF;m++)
        #pragma unroll
        for (int n=0;n<NF;n++)
          acc[m][n] = __builtin_amdgcn_mfma_f32_16x16x32_bf16(a[m], b[n], acc[m][n], 0,0,0);
    }
    __syncthreads();
  }

  if (EPI == 1) {
    #pragma unroll
    for (int m=0;m<MF;m++)
      #pragma unroll
      for (int j=0;j<4;j++) {
        int row = bm*128 + rbase_w + m*16 + (lane>>4)*4 + j;
        #pragma unroll
        for (int n=0;n<NF;n++) {
          int col = bn*128 + cbase_w + n*16 + (lane&15);
          Cf[(size_t)row*N + col] = acc[m][n][j] + bias[col];
        }
      }
  } else {
    const int which = bn >> 4;                // 0=Q, 1=K, 2=V
    const int h = bn & 15;
    if (which < 2) {
      ushort_t* dst = (which==0) ? Qb : Kb;
      #pragma unroll
      for (int m=0;m<MF;m++)
        #pragma unroll
        for (int j=0;j<4;j++) {
          int t = bm*128 + rbase_w + m*16 + (lane>>4)*4 + j;
          int tt = t & (T_-1), bb = t >> 11;
          ushort_t* ptr = dst + ((size_t)(bb*NH + h)*T_ + tt)*HD;
          const float* cb = cosT + tt*64;
          const float* sb = sinT + tt*64;
          #pragma unroll
          for (int n=0;n<4;n++) {
            int d = n*16 + (lane&15);
            float x1 = acc[m][n][j]   + bias[bn*128 + d];
            float x2 = acc[m][n+4][j] + bias[bn*128 + d + 64];
            float cd = cb[d], sd = sb[d];
            ptr[d]    = f2b(x1*cd - x2*sd);
            ptr[d+64] = f2b(x2*cd + x1*sd);
          }
        }
    } else {
      ushort_t* sc = &As[0][0];
      #pragma unroll
      for (int m=0;m<MF;m++)
        #pragma unroll
        for (int j=0;j<4;j++) {
          int r = rbase_w + m*16 + (lane>>4)*4 + j;
          #pragma unroll
          for (int n=0;n<NF;n++) {
            int c = n*16 + (lane&15);
            float v = acc[m][n][j] + bias[bn*128 + c];
            sc[c*128 + (((r>>3)^(c&15))<<3) + (r&7)] = f2b(v);
          }
        }
      __syncthreads();
      int dr = tid >> 1, th = tid & 1;
      int bb = bm >> 4;
      int t0 = (bm & 15)*128 + th*64;
      ushort_t* dstp = Vb + ((size_t)(bb*NH + h)*HD + dr)*T_ + t0;
      #pragma unroll
      for (int k=0;k<8;k++) {
        ushort8v u = *reinterpret_cast<const ushort8v*>(&sc[dr*128 + (((th*8+k)^(dr&15))<<3)]);
        *reinterpret_cast<ushort8v*>(dstp + k*8) = u;
      }
    }
  }
}

// ---------------- flash attention (32x32 core, in-register P via permlane, QBLK=128) ------
// Q,K [BH][T][D]; Vt [BH][D][T]; Y [B,T,C] bf16. 4 waves x 32 q-rows, KVBLK=64.
// R17 note: QBLK=256/512-thread variant regressed (block-tail imbalance) — keep this config.
__global__ __launch_bounds__(256, 2)
void attn_kernel(const ushort_t* __restrict__ Q, const ushort_t* __restrict__ K,
                 const ushort_t* __restrict__ Vt, ushort_t* __restrict__ Y) {
  __shared__ __align__(16) ushort_t Ks[2][64*128];
  __shared__ __align__(16) ushort_t Vs[2][64*128];
  const int tid = threadIdx.x, lane = tid & 63, w = tid >> 6;
  const int ql = lane & 31, hh = lane >> 5;
  const int qtb = (int)gridDim.x - 1 - (int)blockIdx.x;
  const int bh = blockIdx.y;
  const size_t base = (size_t)bh * T_ * HD;
  const int NT = 2*qtb + 2;
  const int qmin = qtb*128 + w*32;
  const int qrow = qmin + ql;

  auto stage = [&](int buf, int kvt) {
    #pragma unroll
    for (int i=0;i<4;i++) {
      int c = i*256 + tid;
      int row = c >> 4, sl = c & 15;
      int g = sl ^ (row & 15);
      gload16(K + base + (size_t)(kvt*64 + row)*HD + g*8, &Ks[buf][c*8]);
    }
    #pragma unroll
    for (int i=0;i<4;i++) {
      int c = i*256 + tid;
      int j = c >> 4, sl = c & 15;
      int g = sl ^ (j & 15);
      int d = 2*j + (g >> 3);
      gload16(Vt + base + (size_t)d*T_ + kvt*64 + (g&7)*8, &Vs[buf][c*8]);
    }
  };

  stage(0, 0);

  bf16x8 qf[8];
  {
    const ushort_t* qp = Q + base + (size_t)qrow*HD + hh*8;
    #pragma unroll
    for (int kb=0; kb<8; ++kb) qf[kb] = *reinterpret_cast<const bf16x8*>(qp + kb*16);
  }

  f32x16 o[4];
  #pragma unroll
  for (int nv=0;nv<4;nv++)
    #pragma unroll
    for (int r=0;r<16;r++) o[nv][r] = 0.f;
  float mi = -1e30f, li = 0.f;
  const float C_ = 0.088388347648318447f * 1.4426950408889634f;
  const float THR = 8.0f / (0.088388347648318447f * 1.4426950408889634f);

  for (int kvt=0; kvt<NT; ++kvt) {
    int cur = kvt & 1;
    if (kvt+1 < NT) {
      stage(cur^1, kvt+1);
      asm volatile("s_waitcnt vmcnt(8)" ::: "memory");
    } else {
      asm volatile("s_waitcnt vmcnt(0)" ::: "memory");
    }
    __builtin_amdgcn_sched_barrier(0);
    __builtin_amdgcn_s_barrier();
    __builtin_amdgcn_sched_barrier(0);

    bool active = (kvt*64 <= qmin + 31);   // wave-uniform
    if (active) {
      f32x16 s0, s1;
      #pragma unroll
      for (int r=0;r<16;r++) { s0[r] = 0.f; s1[r] = 0.f; }
      __builtin_amdgcn_s_setprio(1);
      #pragma unroll
      for (int kb=0;kb<8;kb++) {
        int gl = (kb*2 + hh) ^ (ql & 15);
        bf16x8 kf0 = *reinterpret_cast<const bf16x8*>(&Ks[cur][ql*128 + gl*8]);
        s0 = __builtin_amdgcn_mfma_f32_32x32x16_bf16(kf0, qf[kb], s0, 0,0,0);
        bf16x8 kf1 = *reinterpret_cast<const bf16x8*>(&Ks[cur][(32+ql)*128 + gl*8]);
        s1 = __builtin_amdgcn_mfma_f32_32x32x16_bf16(kf1, qf[kb], s1, 0,0,0);
      }
      __builtin_amdgcn_s_setprio(0);
      bool diag = (kvt*64 + 63 > qmin);
      if (diag) {
        #pragma unroll
        for (int r=0;r<16;r++) {
          int kv0 = kvt*64 + (r&3) + 8*(r>>2) + 4*hh;
          if (kv0 > qrow)      s0[r] = -1e30f;
          if (kv0 + 32 > qrow) s1[r] = -1e30f;
        }
      }
      float pm = fmaxf(s0[0], s1[0]);
      #pragma unroll
      for (int r=1;r<16;r++) pm = fmaxf(pm, fmaxf(s0[r], s1[r]));
      pm = fmaxf(pm, __shfl_xor(pm, 32));
      if (__any(pm > mi + THR)) {
        float mn = fmaxf(mi, pm);
        float alpha = fexp2((mi - mn)*C_);
        mi = mn;
        li *= alpha;
        #pragma unroll
        for (int nv=0;nv<4;nv++)
          #pragma unroll
          for (int r=0;r<16;r++) o[nv][r] *= alpha;
      }
      float p0[16], p1[16];
      #pragma unroll
      for (int r=0;r<16;r++) {
        p0[r] = fexp2((s0[r] - mi)*C_);
        p1[r] = fexp2((s1[r] - mi)*C_);
      }
      float rs = p0[0] + p1[0];
      #pragma unroll
      for (int r=1;r<16;r++) rs += p0[r] + p1[r];
      rs += __shfl_xor(rs, 32);
      li += rs;
      // PV: per-ks2 in-register P fragment (cvt_pk + self-permlane swap + cndmask)
      __builtin_amdgcn_s_setprio(1);
      #pragma unroll
      for (int ks2=0; ks2<4; ++ks2) {
        const int b8 = (ks2&1)*8;
        uint32_t c0 = (ks2<2) ? cvtpk(p0[b8+0], p0[b8+1]) : cvtpk(p1[b8+0], p1[b8+1]);
        uint32_t c1 = (ks2<2) ? cvtpk(p0[b8+2], p0[b8+3]) : cvtpk(p1[b8+2], p1[b8+3]);
        uint32_t c2 = (ks2<2) ? cvtpk(p0[b8+4], p0[b8+5]) : cvtpk(p1[b8+4], p1[b8+5]);
        uint32_t c3 = (ks2<2) ? cvtpk(p0[b8+6], p0[b8+7]) : cvtpk(p1[b8+6], p1[b8+7]);
        uint32_t sw0 = lswap(hh ? c0 : c2);
        uint32_t sw1 = lswap(hh ? c1 : c3);
        u32x4 pw;
        pw[0] = hh ? sw0 : c0;
        pw[1] = hh ? sw1 : c1;
        pw[2] = hh ? c2 : sw0;
        pw[3] = hh ? c3 : sw1;
        bf16x8 pa = __builtin_bit_cast(bf16x8, pw);
        #pragma unroll
        for (int nv=0; nv<4; ++nv) {
          int gv = ((ql&1)*8 + ks2*2 + hh) ^ (ql>>1);
          bf16x8 vf = *reinterpret_cast<const bf16x8*>(&Vs[cur][(nv*16 + (ql>>1))*128 + gv*8]);
          o[nv] = __builtin_amdgcn_mfma_f32_32x32x16_bf16(vf, pa, o[nv], 0,0,0);
        }
      }
      __builtin_amdgcn_s_setprio(0);
    }
    __builtin_amdgcn_s_barrier();
    __builtin_amdgcn_sched_barrier(0);
  }

  int bb = bh >> 4, hd = bh & 15;
  float inv = 1.0f / li;
  size_t rowbase = ((size_t)(bb*T_ + qrow))*D_MODEL + hd*HD;
  #pragma unroll
  for (int nv=0;nv<4;nv++) {
    #pragma unroll
    for (int qd=0;qd<4;qd++) {
      ushort4v r;
      #pragma unroll
      for (int i=0;i<4;i++) r[i] = f2b(o[nv][qd*4+i] * inv);
      *reinterpret_cast<ushort4v*>(&Y[rowbase + nv*32 + 8*qd + 4*hh]) = r;
    }
  }
}

extern "C" void kernel_launch(void* const* d_in, const int* in_sizes, int n_in,
                              void* d_out, int out_size, void* d_ws, size_t ws_size,
                              hipStream_t stream) {
  const float* x      = (const float*)d_in[0];
  const float* W_attn = (const float*)d_in[1];
  const float* b_attn = (const float*)d_in[2];
  const float* W_proj = (const float*)d_in[3];
  const float* b_proj = (const float*)d_in[4];
  float* out = (float*)d_out;

  char* ws = (char*)d_ws;
  size_t off = 0;
  ushort_t* xb = (ushort_t*)(ws + off); off += (size_t)M_*D_MODEL*2;        // 33.5MB
  ushort_t* Wa = (ushort_t*)(ws + off); off += (size_t)3*D_MODEL*D_MODEL*2; // 25.2MB
  ushort_t* Wp = (ushort_t*)(ws + off); off += (size_t)D_MODEL*D_MODEL*2;   // 8.4MB
  ushort_t* Qb = (ushort_t*)(ws + off); off += (size_t)M_*D_MODEL*2;        // 33.5MB
  ushort_t* Kb = (ushort_t*)(ws + off); off += (size_t)M_*D_MODEL*2;        // 33.5MB
  ushort_t* Vtg= (ushort_t*)(ws + off); off += (size_t)M_*D_MODEL*2;        // 33.5MB
  float* cosT = (float*)(ws + off); off += (size_t)T_*64*4;                 // 0.5MB
  float* sinT = (float*)(ws + off); off += (size_t)T_*64*4;                 // 0.5MB
  ushort_t* Yatt = xb;  // alias: xb dead after GEMM1

  prelude_kernel<<<16384 + 12288 + 4096 + 512, 256, 0, stream>>>(
      x, xb, W_attn, Wa, W_proj, Wp, cosT, sinT);

  gemm_kernel<2><<<dim3(64,48), 256, 0, stream>>>(xb, Wa, b_attn, nullptr,
                                                  Qb, Kb, Vtg, cosT, sinT, M_, 3*D_MODEL, D_MODEL);
  attn_kernel<<<dim3(16,64), 256, 0, stream>>>(Qb, Kb, Vtg, Yatt);
  gemm_kernel<1><<<dim3(64,16), 256, 0, stream>>>(Yatt, Wp, b_proj, out,
                                                  nullptr, nullptr, nullptr, nullptr, nullptr,
                                                  M_, D_MODEL, D_MODEL);
}

// Round 19
// 491.095 us; speedup vs baseline: 1.0327x; 1.0177x over previous
//
#include <hip/hip_runtime.h>
#include <hip/hip_bf16.h>
#include <stdint.h>

typedef __bf16 bf16x8 __attribute__((ext_vector_type(8)));
typedef float f32x4 __attribute__((ext_vector_type(4)));
typedef float f32x16 __attribute__((ext_vector_type(16)));
typedef unsigned short ushort_t;
typedef ushort_t ushort4v __attribute__((ext_vector_type(4)));
typedef ushort_t ushort8v __attribute__((ext_vector_type(8)));
typedef float float4v __attribute__((ext_vector_type(4)));
typedef uint32_t u32x4 __attribute__((ext_vector_type(4)));

#define D_MODEL 2048
#define NH 16
#define HD 128
#define B_ 4
#define T_ 2048
#define M_ (B_*T_)

__device__ __forceinline__ float b2f(ushort_t u){ union{uint32_t i; float f;} v; v.i=((uint32_t)u)<<16; return v.f; }
__device__ __forceinline__ ushort_t f2b(float f){ union{float f; uint32_t i;} v; v.f=f; uint32_t r = v.i + 0x7FFFu + ((v.i>>16)&1u); return (ushort_t)(r>>16); }
__device__ __forceinline__ float fexp2(float x){ return __builtin_amdgcn_exp2f(x); }
__device__ __forceinline__ uint32_t cvtpk(float lo, float hi){
  uint32_t r; asm("v_cvt_pk_bf16_f32 %0, %1, %2" : "=v"(r) : "v"(lo), "v"(hi)); return r;
}
__device__ __forceinline__ uint32_t lswap(uint32_t x){
  asm volatile("v_permlane32_swap_b32 %0, %0" : "+v"(x)); return x;
}

__device__ __forceinline__ void gload16(const void* g, void* l) {
  __builtin_amdgcn_global_load_lds((const __attribute__((address_space(1))) void*)g,
                                   (__attribute__((address_space(3))) void*)l, 16, 0, 0);
}

// ---------------- fused prelude: convert x, transpose W_attn, transpose W_proj, RoPE tables ---
__global__ void prelude_kernel(const float* __restrict__ x, ushort_t* __restrict__ xb,
                               const float* __restrict__ W_attn, ushort_t* __restrict__ Wa,
                               const float* __restrict__ W_proj, ushort_t* __restrict__ Wp,
                               float* __restrict__ cosT, float* __restrict__ sinT) {
  __shared__ float tile[32][33];
  const int b = blockIdx.x, tid = threadIdx.x;
  if (b < 16384) {
    int idx = b*256 + tid;
    float4v v = *reinterpret_cast<const float4v*>(x + (size_t)idx*4);
    ushort4v r;
    #pragma unroll
    for (int e=0;e<4;e++) r[e]=f2b(v[e]);
    *reinterpret_cast<ushort4v*>(xb + (size_t)idx*4) = r;
  } else if (b < 16384 + 12288 + 4096) {
    const bool isA = (b < 16384 + 12288);
    const int r = isA ? (b - 16384) : (b - 16384 - 12288);
    const int NW = isA ? 3*D_MODEL : D_MODEL;
    const int nt = isA ? (r % 192) : (r % 64);
    const int kt = isA ? (r / 192) : (r / 64);
    const float* W = isA ? W_attn : W_proj;
    ushort_t* Wt = isA ? Wa : Wp;
    const int xq = tid & 31, yq = tid >> 5;
    #pragma unroll
    for (int i=0;i<4;i++) {
      int k = kt*32 + yq + i*8;
      tile[yq+i*8][xq] = W[(size_t)k*NW + nt*32 + xq];
    }
    __syncthreads();
    #pragma unroll
    for (int i=0;i<4;i++) {
      int n = nt*32 + yq + i*8;
      Wt[(size_t)n*D_MODEL + kt*32 + xq] = f2b(tile[xq][yq+i*8]);
    }
  } else {
    int idx = (b - 16384 - 12288 - 4096)*256 + tid;
    int t = idx >> 6, i = idx & 63;
    float f = powf(10000.0f, -(float)(2*i)/128.0f);
    float ang = (float)t * f;
    cosT[idx] = cosf(ang);
    sinT[idx] = sinf(ang);
  }
}

// ---------------- GEMM: 128x128 tile, BK=64, 4 waves (proven structure) ----------------
// NOTE: no XCD swizzle (R10); no 256²/4-phase (R5/R6/R13 regressed vs this).
template<int EPI>
__global__ __launch_bounds__(256, 2)
void gemm_kernel(const ushort_t* __restrict__ A, const ushort_t* __restrict__ Bt,
                 const float* __restrict__ bias, float* __restrict__ Cf,
                 ushort_t* __restrict__ Qb, ushort_t* __restrict__ Kb, ushort_t* __restrict__ Vb,
                 const float* __restrict__ cosT, const float* __restrict__ sinT,
                 int M, int N, int K) {
  __shared__ __align__(16) ushort_t As[2][128*64];
  __shared__ __align__(16) ushort_t Bs[2][128*64];
  const int tid = threadIdx.x, lane = tid & 63, wid = tid >> 6;
  const int bm = blockIdx.x, bn = blockIdx.y;
  const int nt = K >> 6;
  constexpr int MF = (EPI==2) ? 2 : 4;
  constexpr int NF = (EPI==2) ? 8 : 4;
  const int rbase_w = (EPI==2) ? wid*32 : (wid>>1)*64;
  const int cbase_w = (EPI==2) ? 0      : (wid&1)*64;

  f32x4 acc[MF][NF];
  #pragma unroll
  for (int m=0;m<MF;m++)
    #pragma unroll
    for (int n=0;n<NF;n++) { f32x4 z = {0.f,0.f,0.f,0.f}; acc[m][n] = z; }

  const ushort_t* Abase = A + (size_t)(bm*128)*K;
  const ushort_t* Bbase = Bt + (size_t)(bn*128)*K;

  auto stage = [&](int buf, int kt) {
    const int rsub = (lane>>3);
    const int g = lane & 7;
    #pragma unroll
    for (int i=0;i<4;i++) {
      int chunk = wid*4 + i;
      int row = chunk*8 + rsub;
      int gl = g ^ (row & 7);
      gload16(Abase + (size_t)row*K + kt*64 + gl*8, &As[buf][chunk*512 + lane*8]);
      gload16(Bbase + (size_t)row*K + kt*64 + gl*8, &Bs[buf][chunk*512 + lane*8]);
    }
  };

  stage(0, 0);
  __syncthreads();

  for (int kt=0; kt<nt; ++kt) {
    int cur = kt & 1;
    if (kt+1 < nt) stage(cur^1, kt+1);
    #pragma unroll
    for (int ks=0; ks<2; ++ks) {
      bf16x8 a[MF], b[NF];
      #pragma unroll
      for (int m=0;m<MF;m++) {
        int r = rbase_w + m*16 + (lane&15);
        int gr = (ks*4 + (lane>>4)) ^ (r&7);
        a[m] = *reinterpret_cast<const bf16x8*>(&As[cur][r*64 + gr*8]);
      }
      #pragma unroll
      for (int n=0;n<NF;n++) {
        int r = cbase_w + n*16 + (lane&15);
        int gr = (ks*4 + (lane>>4)) ^ (r&7);
        b[n] = *reinterpret_cast<const bf16x8*>(&Bs[cur][r*64 + gr*8]);
      }
      #pragma unroll
      for (int m=0;m<MF;m++)
        #pragma unroll
        for (int n=0;n<NF;n++)
          acc[m][n] = __builtin_amdgcn_mfma_f32_16x16x32_bf16(a[m], b[n], acc[m][n], 0,0,0);
    }
    __syncthreads();
  }

  if (EPI == 1) {
    #pragma unroll
    for (int m=0;m<MF;m++)
      #pragma unroll
      for (int j=0;j<4;j++) {
        int row = bm*128 + rbase_w + m*16 + (lane>>4)*4 + j;
        #pragma unroll
        for (int n=0;n<NF;n++) {
          int col = bn*128 + cbase_w + n*16 + (lane&15);
          Cf[(size_t)row*N + col] = acc[m][n][j] + bias[col];
        }
      }
  } else {
    const int which = bn >> 4;                // 0=Q, 1=K, 2=V
    const int h = bn & 15;
    if (which < 2) {
      ushort_t* dst = (which==0) ? Qb : Kb;
      #pragma unroll
      for (int m=0;m<MF;m++)
        #pragma unroll
        for (int j=0;j<4;j++) {
          int t = bm*128 + rbase_w + m*16 + (lane>>4)*4 + j;
          int tt = t & (T_-1), bb = t >> 11;
          ushort_t* ptr = dst + ((size_t)(bb*NH + h)*T_ + tt)*HD;
          const float* cb = cosT + tt*64;
          const float* sb = sinT + tt*64;
          #pragma unroll
          for (int n=0;n<4;n++) {
            int d = n*16 + (lane&15);
            float x1 = acc[m][n][j]   + bias[bn*128 + d];
            float x2 = acc[m][n+4][j] + bias[bn*128 + d + 64];
            float cd = cb[d], sd = sb[d];
            ptr[d]    = f2b(x1*cd - x2*sd);
            ptr[d+64] = f2b(x2*cd + x1*sd);
          }
        }
    } else {
      ushort_t* sc = &As[0][0];
      #pragma unroll
      for (int m=0;m<MF;m++)
        #pragma unroll
        for (int j=0;j<4;j++) {
          int r = rbase_w + m*16 + (lane>>4)*4 + j;
          #pragma unroll
          for (int n=0;n<NF;n++) {
            int c = n*16 + (lane&15);
            float v = acc[m][n][j] + bias[bn*128 + c];
            sc[c*128 + (((r>>3)^(c&15))<<3) + (r&7)] = f2b(v);
          }
        }
      __syncthreads();
      int dr = tid >> 1, th = tid & 1;
      int bb = bm >> 4;
      int t0 = (bm & 15)*128 + th*64;
      ushort_t* dstp = Vb + ((size_t)(bb*NH + h)*HD + dr)*T_ + t0;
      #pragma unroll
      for (int k=0;k<8;k++) {
        ushort8v u = *reinterpret_cast<const ushort8v*>(&sc[dr*128 + (((th*8+k)^(dr&15))<<3)]);
        *reinterpret_cast<ushort8v*>(dstp + k*8) = u;
      }
    }
  }
}

// ---------------- flash attention (32x32 core, in-register P, V single-buffered) ----------
// Q,K [BH][T][D]; Vt [BH][D][T]; Y [B,T,C] bf16. QBLK=128 (4 waves x 32 q-rows), KVBLK=64.
// K double-buffered, V single-buffered: LDS 48KB -> 3 blocks/CU (was 2).
// Per tile: stage V[t]; stage K[t+1]; vmcnt(K-own) barrier; QK^T+softmax;
//           vmcnt(V-own) barrier; PV; end barrier. Hazards separated by end barrier.
__global__ __launch_bounds__(256, 2)
void attn_kernel(const ushort_t* __restrict__ Q, const ushort_t* __restrict__ K,
                 const ushort_t* __restrict__ Vt, ushort_t* __restrict__ Y) {
  __shared__ __align__(16) ushort_t Ks[2][64*128];   // 32KB dbuf
  __shared__ __align__(16) ushort_t Vs[64*128];      // 16KB single (row j = d>>1)
  const int tid = threadIdx.x, lane = tid & 63, w = tid >> 6;
  const int ql = lane & 31, hh = lane >> 5;
  const int qtb = (int)gridDim.x - 1 - (int)blockIdx.x;
  const int bh = blockIdx.y;
  const size_t base = (size_t)bh * T_ * HD;
  const int NT = 2*qtb + 2;
  const int qmin = qtb*128 + w*32;
  const int qrow = qmin + ql;

  auto stageK = [&](int buf, int kvt) {
    #pragma unroll
    for (int i=0;i<4;i++) {
      int c = i*256 + tid;
      int row = c >> 4, sl = c & 15;
      int g = sl ^ (row & 15);
      gload16(K + base + (size_t)(kvt*64 + row)*HD + g*8, &Ks[buf][c*8]);
    }
  };
  auto stageV = [&](int kvt) {
    #pragma unroll
    for (int i=0;i<4;i++) {
      int c = i*256 + tid;
      int j = c >> 4, sl = c & 15;
      int g = sl ^ (j & 15);
      int d = 2*j + (g >> 3);
      gload16(Vt + base + (size_t)d*T_ + kvt*64 + (g&7)*8, &Vs[c*8]);
    }
  };

  stageK(0, 0);

  bf16x8 qf[8];
  {
    const ushort_t* qp = Q + base + (size_t)qrow*HD + hh*8;
    #pragma unroll
    for (int kb=0; kb<8; ++kb) qf[kb] = *reinterpret_cast<const bf16x8*>(qp + kb*16);
  }

  f32x16 o[4];
  #pragma unroll
  for (int nv=0;nv<4;nv++)
    #pragma unroll
    for (int r=0;r<16;r++) o[nv][r] = 0.f;
  float mi = -1e30f, li = 0.f;
  const float C_ = 0.088388347648318447f * 1.4426950408889634f;
  const float THR = 8.0f / (0.088388347648318447f * 1.4426950408889634f);

  for (int kvt=0; kvt<NT; ++kvt) {
    int cur = kvt & 1;
    bool pf = (kvt+1 < NT);
    stageV(kvt);                                 // into single Vs (readers done: end barrier t-1)
    if (pf) stageK(cur^1, kvt+1);
    // wait K[kvt] (oldest 4): outstanding = V[kvt](4) + K[kvt+1](4 if pf)
    if (pf) asm volatile("s_waitcnt vmcnt(8)" ::: "memory");
    else    asm volatile("s_waitcnt vmcnt(4)" ::: "memory");
    __builtin_amdgcn_sched_barrier(0);
    __builtin_amdgcn_s_barrier();
    __builtin_amdgcn_sched_barrier(0);

    bool active = (kvt*64 <= qmin + 31);   // wave-uniform
    f32x16 s0, s1;
    float p0[16], p1[16];
    if (active) {
      #pragma unroll
      for (int r=0;r<16;r++) { s0[r] = 0.f; s1[r] = 0.f; }
      __builtin_amdgcn_s_setprio(1);
      #pragma unroll
      for (int kb=0;kb<8;kb++) {
        int gl = (kb*2 + hh) ^ (ql & 15);
        bf16x8 kf0 = *reinterpret_cast<const bf16x8*>(&Ks[cur][ql*128 + gl*8]);
        s0 = __builtin_amdgcn_mfma_f32_32x32x16_bf16(kf0, qf[kb], s0, 0,0,0);
        bf16x8 kf1 = *reinterpret_cast<const bf16x8*>(&Ks[cur][(32+ql)*128 + gl*8]);
        s1 = __builtin_amdgcn_mfma_f32_32x32x16_bf16(kf1, qf[kb], s1, 0,0,0);
      }
      __builtin_amdgcn_s_setprio(0);
      bool diag = (kvt*64 + 63 > qmin);
      if (diag) {
        #pragma unroll
        for (int r=0;r<16;r++) {
          int kv0 = kvt*64 + (r&3) + 8*(r>>2) + 4*hh;
          if (kv0 > qrow)      s0[r] = -1e30f;
          if (kv0 + 32 > qrow) s1[r] = -1e30f;
        }
      }
      float pm = fmaxf(s0[0], s1[0]);
      #pragma unroll
      for (int r=1;r<16;r++) pm = fmaxf(pm, fmaxf(s0[r], s1[r]));
      pm = fmaxf(pm, __shfl_xor(pm, 32));
      if (__any(pm > mi + THR)) {
        float mn = fmaxf(mi, pm);
        float alpha = fexp2((mi - mn)*C_);
        mi = mn;
        li *= alpha;
        #pragma unroll
        for (int nv=0;nv<4;nv++)
          #pragma unroll
          for (int r=0;r<16;r++) o[nv][r] *= alpha;
      }
      #pragma unroll
      for (int r=0;r<16;r++) {
        p0[r] = fexp2((s0[r] - mi)*C_);
        p1[r] = fexp2((s1[r] - mi)*C_);
      }
      float rs = p0[0] + p1[0];
      #pragma unroll
      for (int r=1;r<16;r++) rs += p0[r] + p1[r];
      rs += __shfl_xor(rs, 32);
      li += rs;
    }
    // wait V[kvt] (own loads), then barrier so ALL waves' V chunks are in LDS
    if (pf) asm volatile("s_waitcnt vmcnt(4)" ::: "memory");
    else    asm volatile("s_waitcnt vmcnt(0)" ::: "memory");
    __builtin_amdgcn_sched_barrier(0);
    __builtin_amdgcn_s_barrier();
    __builtin_amdgcn_sched_barrier(0);
    if (active) {
      // PV: per-ks2 in-register P fragment (cvt_pk + self-permlane swap + cndmask)
      __builtin_amdgcn_s_setprio(1);
      #pragma unroll
      for (int ks2=0; ks2<4; ++ks2) {
        const int b8 = (ks2&1)*8;
        uint32_t c0 = (ks2<2) ? cvtpk(p0[b8+0], p0[b8+1]) : cvtpk(p1[b8+0], p1[b8+1]);
        uint32_t c1 = (ks2<2) ? cvtpk(p0[b8+2], p0[b8+3]) : cvtpk(p1[b8+2], p1[b8+3]);
        uint32_t c2 = (ks2<2) ? cvtpk(p0[b8+4], p0[b8+5]) : cvtpk(p1[b8+4], p1[b8+5]);
        uint32_t c3 = (ks2<2) ? cvtpk(p0[b8+6], p0[b8+7]) : cvtpk(p1[b8+6], p1[b8+7]);
        uint32_t sw0 = lswap(hh ? c0 : c2);
        uint32_t sw1 = lswap(hh ? c1 : c3);
        u32x4 pw;
        pw[0] = hh ? sw0 : c0;
        pw[1] = hh ? sw1 : c1;
        pw[2] = hh ? c2 : sw0;
        pw[3] = hh ? c3 : sw1;
        bf16x8 pa = __builtin_bit_cast(bf16x8, pw);
        #pragma unroll
        for (int nv=0; nv<4; ++nv) {
          int gv = ((ql&1)*8 + ks2*2 + hh) ^ (ql>>1);
          bf16x8 vf = *reinterpret_cast<const bf16x8*>(&Vs[(nv*16 + (ql>>1))*128 + gv*8]);
          o[nv] = __builtin_amdgcn_mfma_f32_32x32x16_bf16(vf, pa, o[nv], 0,0,0);
        }
      }
      __builtin_amdgcn_s_setprio(0);
    }
    __builtin_amdgcn_s_barrier();            // readers done before next V restage / K stage
    __builtin_amdgcn_sched_barrier(0);
  }

  int bb = bh >> 4, hd = bh & 15;
  float inv = 1.0f / li;
  size_t rowbase = ((size_t)(bb*T_ + qrow))*D_MODEL + hd*HD;
  #pragma unroll
  for (int nv=0;nv<4;nv++) {
    #pragma unroll
    for (int qd=0;qd<4;qd++) {
      ushort4v r;
      #pragma unroll
      for (int i=0;i<4;i++) r[i] = f2b(o[nv][qd*4+i] * inv);
      *reinterpret_cast<ushort4v*>(&Y[rowbase + nv*32 + 8*qd + 4*hh]) = r;
    }
  }
}

extern "C" void kernel_launch(void* const* d_in, const int* in_sizes, int n_in,
                              void* d_out, int out_size, void* d_ws, size_t ws_size,
                              hipStream_t stream) {
  const float* x      = (const float*)d_in[0];
  const float* W_attn = (const float*)d_in[1];
  const float* b_attn = (const float*)d_in[2];
  const float* W_proj = (const float*)d_in[3];
  const float* b_proj = (const float*)d_in[4];
  float* out = (float*)d_out;

  char* ws = (char*)d_ws;
  size_t off = 0;
  ushort_t* xb = (ushort_t*)(ws + off); off += (size_t)M_*D_MODEL*2;        // 33.5MB
  ushort_t* Wa = (ushort_t*)(ws + off); off += (size_t)3*D_MODEL*D_MODEL*2; // 25.2MB
  ushort_t* Wp = (ushort_t*)(ws + off); off += (size_t)D_MODEL*D_MODEL*2;   // 8.4MB
  ushort_t* Qb = (ushort_t*)(ws + off); off += (size_t)M_*D_MODEL*2;        // 33.5MB
  ushort_t* Kb = (ushort_t*)(ws + off); off += (size_t)M_*D_MODEL*2;        // 33.5MB
  ushort_t* Vtg= (ushort_t*)(ws + off); off += (size_t)M_*D_MODEL*2;        // 33.5MB
  float* cosT = (float*)(ws + off); off += (size_t)T_*64*4;                 // 0.5MB
  float* sinT = (float*)(ws + off); off += (size_t)T_*64*4;                 // 0.5MB
  ushort_t* Yatt = xb;  // alias: xb dead after GEMM1

  prelude_kernel<<<16384 + 12288 + 4096 + 512, 256, 0, stream>>>(
      x, xb, W_attn, Wa, W_proj, Wp, cosT, sinT);

  gemm_kernel<2><<<dim3(64,48), 256, 0, stream>>>(xb, Wa, b_attn, nullptr,
                                                  Qb, Kb, Vtg, cosT, sinT, M_, 3*D_MODEL, D_MODEL);
  attn_kernel<<<dim3(16,64), 256, 0, stream>>>(Qb, Kb, Vtg, Yatt);
  gemm_kernel<1><<<dim3(64,16), 256, 0, stream>>>(Yatt, Wp, b_proj, out,
                                                  nullptr, nullptr, nullptr, nullptr, nullptr,
                                                  M_, D_MODEL, D_MODEL);
}

// Round 20
// 447.782 us; speedup vs baseline: 1.1326x; 1.0967x over previous
//
#include <hip/hip_runtime.h>
#include <hip/hip_bf16.h>
#include <stdint.h>

typedef __bf16 bf16x8 __attribute__((ext_vector_type(8)));
typedef float f32x4 __attribute__((ext_vector_type(4)));
typedef float f32x16 __attribute__((ext_vector_type(16)));
typedef unsigned short ushort_t;
typedef ushort_t ushort4v __attribute__((ext_vector_type(4)));
typedef ushort_t ushort8v __attribute__((ext_vector_type(8)));
typedef float float4v __attribute__((ext_vector_type(4)));
typedef uint32_t u32x4 __attribute__((ext_vector_type(4)));

#define D_MODEL 2048
#define NH 16
#define HD 128
#define B_ 4
#define T_ 2048
#define M_ (B_*T_)

__device__ __forceinline__ float b2f(ushort_t u){ union{uint32_t i; float f;} v; v.i=((uint32_t)u)<<16; return v.f; }
__device__ __forceinline__ ushort_t f2b(float f){ union{float f; uint32_t i;} v; v.f=f; uint32_t r = v.i + 0x7FFFu + ((v.i>>16)&1u); return (ushort_t)(r>>16); }
__device__ __forceinline__ float fexp2(float x){ return __builtin_amdgcn_exp2f(x); }
__device__ __forceinline__ uint32_t cvtpk(float lo, float hi){
  uint32_t r; asm("v_cvt_pk_bf16_f32 %0, %1, %2" : "=v"(r) : "v"(lo), "v"(hi)); return r;
}
__device__ __forceinline__ uint32_t lswap(uint32_t x){
  asm volatile("v_permlane32_swap_b32 %0, %0" : "+v"(x)); return x;
}

__device__ __forceinline__ void gload16(const void* g, void* l) {
  __builtin_amdgcn_global_load_lds((const __attribute__((address_space(1))) void*)g,
                                   (__attribute__((address_space(3))) void*)l, 16, 0, 0);
}

// ---------------- fused prelude: convert x, transpose W_attn, transpose W_proj, RoPE tables ---
__global__ void prelude_kernel(const float* __restrict__ x, ushort_t* __restrict__ xb,
                               const float* __restrict__ W_attn, ushort_t* __restrict__ Wa,
                               const float* __restrict__ W_proj, ushort_t* __restrict__ Wp,
                               float* __restrict__ cosT, float* __restrict__ sinT) {
  __shared__ float tile[32][33];
  const int b = blockIdx.x, tid = threadIdx.x;
  if (b < 16384) {
    int idx = b*256 + tid;
    float4v v = *reinterpret_cast<const float4v*>(x + (size_t)idx*4);
    ushort4v r;
    #pragma unroll
    for (int e=0;e<4;e++) r[e]=f2b(v[e]);
    *reinterpret_cast<ushort4v*>(xb + (size_t)idx*4) = r;
  } else if (b < 16384 + 12288 + 4096) {
    const bool isA = (b < 16384 + 12288);
    const int r = isA ? (b - 16384) : (b - 16384 - 12288);
    const int NW = isA ? 3*D_MODEL : D_MODEL;
    const int nt = isA ? (r % 192) : (r % 64);
    const int kt = isA ? (r / 192) : (r / 64);
    const float* W = isA ? W_attn : W_proj;
    ushort_t* Wt = isA ? Wa : Wp;
    const int xq = tid & 31, yq = tid >> 5;
    #pragma unroll
    for (int i=0;i<4;i++) {
      int k = kt*32 + yq + i*8;
      tile[yq+i*8][xq] = W[(size_t)k*NW + nt*32 + xq];
    }
    __syncthreads();
    #pragma unroll
    for (int i=0;i<4;i++) {
      int n = nt*32 + yq + i*8;
      Wt[(size_t)n*D_MODEL + kt*32 + xq] = f2b(tile[xq][yq+i*8]);
    }
  } else {
    int idx = (b - 16384 - 12288 - 4096)*256 + tid;
    int t = idx >> 6, i = idx & 63;
    float f = powf(10000.0f, -(float)(2*i)/128.0f);
    float ang = (float)t * f;
    cosT[idx] = cosf(ang);
    sinT[idx] = sinf(ang);
  }
}

// ---------------- GEMM: 128x128 tile, BK=64, 4 waves (proven structure) ----------------
// NOTE: no XCD swizzle (R10); no 256²/4-phase (R5/R6/R13 regressed vs this).
template<int EPI>
__global__ __launch_bounds__(256, 2)
void gemm_kernel(const ushort_t* __restrict__ A, const ushort_t* __restrict__ Bt,
                 const float* __restrict__ bias, float* __restrict__ Cf,
                 ushort_t* __restrict__ Qb, ushort_t* __restrict__ Kb, ushort_t* __restrict__ Vb,
                 const float* __restrict__ cosT, const float* __restrict__ sinT,
                 int M, int N, int K) {
  __shared__ __align__(16) ushort_t As[2][128*64];
  __shared__ __align__(16) ushort_t Bs[2][128*64];
  const int tid = threadIdx.x, lane = tid & 63, wid = tid >> 6;
  const int bm = blockIdx.x, bn = blockIdx.y;
  const int nt = K >> 6;
  constexpr int MF = (EPI==2) ? 2 : 4;
  constexpr int NF = (EPI==2) ? 8 : 4;
  const int rbase_w = (EPI==2) ? wid*32 : (wid>>1)*64;
  const int cbase_w = (EPI==2) ? 0      : (wid&1)*64;

  f32x4 acc[MF][NF];
  #pragma unroll
  for (int m=0;m<MF;m++)
    #pragma unroll
    for (int n=0;n<NF;n++) { f32x4 z = {0.f,0.f,0.f,0.f}; acc[m][n] = z; }

  const ushort_t* Abase = A + (size_t)(bm*128)*K;
  const ushort_t* Bbase = Bt + (size_t)(bn*128)*K;

  auto stage = [&](int buf, int kt) {
    const int rsub = (lane>>3);
    const int g = lane & 7;
    #pragma unroll
    for (int i=0;i<4;i++) {
      int chunk = wid*4 + i;
      int row = chunk*8 + rsub;
      int gl = g ^ (row & 7);
      gload16(Abase + (size_t)row*K + kt*64 + gl*8, &As[buf][chunk*512 + lane*8]);
      gload16(Bbase + (size_t)row*K + kt*64 + gl*8, &Bs[buf][chunk*512 + lane*8]);
    }
  };

  stage(0, 0);
  __syncthreads();

  for (int kt=0; kt<nt; ++kt) {
    int cur = kt & 1;
    if (kt+1 < nt) stage(cur^1, kt+1);
    #pragma unroll
    for (int ks=0; ks<2; ++ks) {
      bf16x8 a[MF], b[NF];
      #pragma unroll
      for (int m=0;m<MF;m++) {
        int r = rbase_w + m*16 + (lane&15);
        int gr = (ks*4 + (lane>>4)) ^ (r&7);
        a[m] = *reinterpret_cast<const bf16x8*>(&As[cur][r*64 + gr*8]);
      }
      #pragma unroll
      for (int n=0;n<NF;n++) {
        int r = cbase_w + n*16 + (lane&15);
        int gr = (ks*4 + (lane>>4)) ^ (r&7);
        b[n] = *reinterpret_cast<const bf16x8*>(&Bs[cur][r*64 + gr*8]);
      }
      #pragma unroll
      for (int m=0;m<MF;m++)
        #pragma unroll
        for (int n=0;n<NF;n++)
          acc[m][n] = __builtin_amdgcn_mfma_f32_16x16x32_bf16(a[m], b[n], acc[m][n], 0,0,0);
    }
    __syncthreads();
  }

  if (EPI == 1) {
    #pragma unroll
    for (int m=0;m<MF;m++)
      #pragma unroll
      for (int j=0;j<4;j++) {
        int row = bm*128 + rbase_w + m*16 + (lane>>4)*4 + j;
        #pragma unroll
        for (int n=0;n<NF;n++) {
          int col = bn*128 + cbase_w + n*16 + (lane&15);
          Cf[(size_t)row*N + col] = acc[m][n][j] + bias[col];
        }
      }
  } else {
    const int which = bn >> 4;                // 0=Q, 1=K, 2=V
    const int h = bn & 15;
    if (which < 2) {
      ushort_t* dst = (which==0) ? Qb : Kb;
      #pragma unroll
      for (int m=0;m<MF;m++)
        #pragma unroll
        for (int j=0;j<4;j++) {
          int t = bm*128 + rbase_w + m*16 + (lane>>4)*4 + j;
          int tt = t & (T_-1), bb = t >> 11;
          ushort_t* ptr = dst + ((size_t)(bb*NH + h)*T_ + tt)*HD;
          const float* cb = cosT + tt*64;
          const float* sb = sinT + tt*64;
          #pragma unroll
          for (int n=0;n<4;n++) {
            int d = n*16 + (lane&15);
            float x1 = acc[m][n][j]   + bias[bn*128 + d];
            float x2 = acc[m][n+4][j] + bias[bn*128 + d + 64];
            float cd = cb[d], sd = sb[d];
            ptr[d]    = f2b(x1*cd - x2*sd);
            ptr[d+64] = f2b(x2*cd + x1*sd);
          }
        }
    } else {
      ushort_t* sc = &As[0][0];
      #pragma unroll
      for (int m=0;m<MF;m++)
        #pragma unroll
        for (int j=0;j<4;j++) {
          int r = rbase_w + m*16 + (lane>>4)*4 + j;
          #pragma unroll
          for (int n=0;n<NF;n++) {
            int c = n*16 + (lane&15);
            float v = acc[m][n][j] + bias[bn*128 + c];
            sc[c*128 + (((r>>3)^(c&15))<<3) + (r&7)] = f2b(v);
          }
        }
      __syncthreads();
      int dr = tid >> 1, th = tid & 1;
      int bb = bm >> 4;
      int t0 = (bm & 15)*128 + th*64;
      ushort_t* dstp = Vb + ((size_t)(bb*NH + h)*HD + dr)*T_ + t0;
      #pragma unroll
      for (int k=0;k<8;k++) {
        ushort8v u = *reinterpret_cast<const ushort8v*>(&sc[dr*128 + (((th*8+k)^(dr&15))<<3)]);
        *reinterpret_cast<ushort8v*>(dstp + k*8) = u;
      }
    }
  }
}

// ---------------- flash attention (32x32 core, in-register P, V single-buffered) ----------
// Q,K [BH][T][D]; Vt [BH][D][T]; Y [B,T,C] bf16. QBLK=128 (4 waves x 32 q-rows), KVBLK=64.
// K dbuf + V single buffer: LDS 48KB -> 3 blocks/CU. 1D grid, GLOBAL heavy-first order:
// qtb = 15 - (id>>6) so all 64 heaviest blocks dispatch first (tail packs lights).
__global__ __launch_bounds__(256, 2)
void attn_kernel(const ushort_t* __restrict__ Q, const ushort_t* __restrict__ K,
                 const ushort_t* __restrict__ Vt, ushort_t* __restrict__ Y) {
  __shared__ __align__(16) ushort_t Ks[2][64*128];   // 32KB dbuf
  __shared__ __align__(16) ushort_t Vs[64*128];      // 16KB single (row j = d>>1)
  const int tid = threadIdx.x, lane = tid & 63, w = tid >> 6;
  const int ql = lane & 31, hh = lane >> 5;
  const int id = blockIdx.x;
  const int qtb = 15 - (id >> 6);                    // global heavy-first
  const int bh = id & 63;
  const size_t base = (size_t)bh * T_ * HD;
  const int NT = 2*qtb + 2;
  const int qmin = qtb*128 + w*32;
  const int qrow = qmin + ql;

  auto stageK = [&](int buf, int kvt) {
    #pragma unroll
    for (int i=0;i<4;i++) {
      int c = i*256 + tid;
      int row = c >> 4, sl = c & 15;
      int g = sl ^ (row & 15);
      gload16(K + base + (size_t)(kvt*64 + row)*HD + g*8, &Ks[buf][c*8]);
    }
  };
  auto stageV = [&](int kvt) {
    #pragma unroll
    for (int i=0;i<4;i++) {
      int c = i*256 + tid;
      int j = c >> 4, sl = c & 15;
      int g = sl ^ (j & 15);
      int d = 2*j + (g >> 3);
      gload16(Vt + base + (size_t)d*T_ + kvt*64 + (g&7)*8, &Vs[c*8]);
    }
  };

  stageK(0, 0);

  bf16x8 qf[8];
  {
    const ushort_t* qp = Q + base + (size_t)qrow*HD + hh*8;
    #pragma unroll
    for (int kb=0; kb<8; ++kb) qf[kb] = *reinterpret_cast<const bf16x8*>(qp + kb*16);
  }

  f32x16 o[4];
  #pragma unroll
  for (int nv=0;nv<4;nv++)
    #pragma unroll
    for (int r=0;r<16;r++) o[nv][r] = 0.f;
  float mi = -1e30f, li = 0.f;
  const float C_ = 0.088388347648318447f * 1.4426950408889634f;
  const float THR = 8.0f / (0.088388347648318447f * 1.4426950408889634f);

  for (int kvt=0; kvt<NT; ++kvt) {
    int cur = kvt & 1;
    bool pf = (kvt+1 < NT);
    stageV(kvt);                                 // into single Vs (readers done: end barrier t-1)
    if (pf) stageK(cur^1, kvt+1);
    // wait K[kvt] (oldest 4): outstanding = V[kvt](4) + K[kvt+1](4 if pf)
    if (pf) asm volatile("s_waitcnt vmcnt(8)" ::: "memory");
    else    asm volatile("s_waitcnt vmcnt(4)" ::: "memory");
    __builtin_amdgcn_sched_barrier(0);
    __builtin_amdgcn_s_barrier();
    __builtin_amdgcn_sched_barrier(0);

    bool active = (kvt*64 <= qmin + 31);   // wave-uniform
    f32x16 s0, s1;
    float p0[16], p1[16];
    if (active) {
      #pragma unroll
      for (int r=0;r<16;r++) { s0[r] = 0.f; s1[r] = 0.f; }
      __builtin_amdgcn_s_setprio(1);
      #pragma unroll
      for (int kb=0;kb<8;kb++) {
        int gl = (kb*2 + hh) ^ (ql & 15);
        bf16x8 kf0 = *reinterpret_cast<const bf16x8*>(&Ks[cur][ql*128 + gl*8]);
        s0 = __builtin_amdgcn_mfma_f32_32x32x16_bf16(kf0, qf[kb], s0, 0,0,0);
        bf16x8 kf1 = *reinterpret_cast<const bf16x8*>(&Ks[cur][(32+ql)*128 + gl*8]);
        s1 = __builtin_amdgcn_mfma_f32_32x32x16_bf16(kf1, qf[kb], s1, 0,0,0);
      }
      __builtin_amdgcn_s_setprio(0);
      bool diag = (kvt*64 + 63 > qmin);
      if (diag) {
        #pragma unroll
        for (int r=0;r<16;r++) {
          int kv0 = kvt*64 + (r&3) + 8*(r>>2) + 4*hh;
          if (kv0 > qrow)      s0[r] = -1e30f;
          if (kv0 + 32 > qrow) s1[r] = -1e30f;
        }
      }
      float pm = fmaxf(s0[0], s1[0]);
      #pragma unroll
      for (int r=1;r<16;r++) pm = fmaxf(pm, fmaxf(s0[r], s1[r]));
      pm = fmaxf(pm, __shfl_xor(pm, 32));
      if (__any(pm > mi + THR)) {
        float mn = fmaxf(mi, pm);
        float alpha = fexp2((mi - mn)*C_);
        mi = mn;
        li *= alpha;
        #pragma unroll
        for (int nv=0;nv<4;nv++)
          #pragma unroll
          for (int r=0;r<16;r++) o[nv][r] *= alpha;
      }
      #pragma unroll
      for (int r=0;r<16;r++) {
        p0[r] = fexp2((s0[r] - mi)*C_);
        p1[r] = fexp2((s1[r] - mi)*C_);
      }
      float rs = p0[0] + p1[0];
      #pragma unroll
      for (int r=1;r<16;r++) rs += p0[r] + p1[r];
      rs += __shfl_xor(rs, 32);
      li += rs;
    }
    // wait V[kvt] (own loads), then barrier so ALL waves' V chunks are in LDS
    if (pf) asm volatile("s_waitcnt vmcnt(4)" ::: "memory");
    else    asm volatile("s_waitcnt vmcnt(0)" ::: "memory");
    __builtin_amdgcn_sched_barrier(0);
    __builtin_amdgcn_s_barrier();
    __builtin_amdgcn_sched_barrier(0);
    if (active) {
      // PV: per-ks2 in-register P fragment (cvt_pk + self-permlane swap + cndmask)
      __builtin_amdgcn_s_setprio(1);
      #pragma unroll
      for (int ks2=0; ks2<4; ++ks2) {
        const int b8 = (ks2&1)*8;
        uint32_t c0 = (ks2<2) ? cvtpk(p0[b8+0], p0[b8+1]) : cvtpk(p1[b8+0], p1[b8+1]);
        uint32_t c1 = (ks2<2) ? cvtpk(p0[b8+2], p0[b8+3]) : cvtpk(p1[b8+2], p1[b8+3]);
        uint32_t c2 = (ks2<2) ? cvtpk(p0[b8+4], p0[b8+5]) : cvtpk(p1[b8+4], p1[b8+5]);
        uint32_t c3 = (ks2<2) ? cvtpk(p0[b8+6], p0[b8+7]) : cvtpk(p1[b8+6], p1[b8+7]);
        uint32_t sw0 = lswap(hh ? c0 : c2);
        uint32_t sw1 = lswap(hh ? c1 : c3);
        u32x4 pw;
        pw[0] = hh ? sw0 : c0;
        pw[1] = hh ? sw1 : c1;
        pw[2] = hh ? c2 : sw0;
        pw[3] = hh ? c3 : sw1;
        bf16x8 pa = __builtin_bit_cast(bf16x8, pw);
        #pragma unroll
        for (int nv=0; nv<4; ++nv) {
          int gv = ((ql&1)*8 + ks2*2 + hh) ^ (ql>>1);
          bf16x8 vf = *reinterpret_cast<const bf16x8*>(&Vs[(nv*16 + (ql>>1))*128 + gv*8]);
          o[nv] = __builtin_amdgcn_mfma_f32_32x32x16_bf16(vf, pa, o[nv], 0,0,0);
        }
      }
      __builtin_amdgcn_s_setprio(0);
    }
    __builtin_amdgcn_s_barrier();            // readers done before next V restage / K stage
    __builtin_amdgcn_sched_barrier(0);
  }

  int bb = bh >> 4, hd = bh & 15;
  float inv = 1.0f / li;
  size_t rowbase = ((size_t)(bb*T_ + qrow))*D_MODEL + hd*HD;
  #pragma unroll
  for (int nv=0;nv<4;nv++) {
    #pragma unroll
    for (int qd=0;qd<4;qd++) {
      ushort4v r;
      #pragma unroll
      for (int i=0;i<4;i++) r[i] = f2b(o[nv][qd*4+i] * inv);
      *reinterpret_cast<ushort4v*>(&Y[rowbase + nv*32 + 8*qd + 4*hh]) = r;
    }
  }
}

extern "C" void kernel_launch(void* const* d_in, const int* in_sizes, int n_in,
                              void* d_out, int out_size, void* d_ws, size_t ws_size,
                              hipStream_t stream) {
  const float* x      = (const float*)d_in[0];
  const float* W_attn = (const float*)d_in[1];
  const float* b_attn = (const float*)d_in[2];
  const float* W_proj = (const float*)d_in[3];
  const float* b_proj = (const float*)d_in[4];
  float* out = (float*)d_out;

  char* ws = (char*)d_ws;
  size_t off = 0;
  ushort_t* xb = (ushort_t*)(ws + off); off += (size_t)M_*D_MODEL*2;        // 33.5MB
  ushort_t* Wa = (ushort_t*)(ws + off); off += (size_t)3*D_MODEL*D_MODEL*2; // 25.2MB
  ushort_t* Wp = (ushort_t*)(ws + off); off += (size_t)D_MODEL*D_MODEL*2;   // 8.4MB
  ushort_t* Qb = (ushort_t*)(ws + off); off += (size_t)M_*D_MODEL*2;        // 33.5MB
  ushort_t* Kb = (ushort_t*)(ws + off); off += (size_t)M_*D_MODEL*2;        // 33.5MB
  ushort_t* Vtg= (ushort_t*)(ws + off); off += (size_t)M_*D_MODEL*2;        // 33.5MB
  float* cosT = (float*)(ws + off); off += (size_t)T_*64*4;                 // 0.5MB
  float* sinT = (float*)(ws + off); off += (size_t)T_*64*4;                 // 0.5MB
  ushort_t* Yatt = xb;  // alias: xb dead after GEMM1

  prelude_kernel<<<16384 + 12288 + 4096 + 512, 256, 0, stream>>>(
      x, xb, W_attn, Wa, W_proj, Wp, cosT, sinT);

  gemm_kernel<2><<<dim3(64,48), 256, 0, stream>>>(xb, Wa, b_attn, nullptr,
                                                  Qb, Kb, Vtg, cosT, sinT, M_, 3*D_MODEL, D_MODEL);
  attn_kernel<<<dim3(1024), 256, 0, stream>>>(Qb, Kb, Vtg, Yatt);
  gemm_kernel<1><<<dim3(64,16), 256, 0, stream>>>(Yatt, Wp, b_proj, out,
                                                  nullptr, nullptr, nullptr, nullptr, nullptr,
                                                  M_, D_MODEL, D_MODEL);
}

// Round 21
// 403.250 us; speedup vs baseline: 1.2576x; 1.1104x over previous
//
#include <hip/hip_runtime.h>
#include <hip/hip_bf16.h>
#include <stdint.h>

typedef __bf16 bf16x8 __attribute__((ext_vector_type(8)));
typedef float f32x4 __attribute__((ext_vector_type(4)));
typedef float f32x16 __attribute__((ext_vector_type(16)));
typedef unsigned short ushort_t;
typedef ushort_t ushort4v __attribute__((ext_vector_type(4)));
typedef ushort_t ushort8v __attribute__((ext_vector_type(8)));
typedef float float4v __attribute__((ext_vector_type(4)));
typedef uint32_t u32x4 __attribute__((ext_vector_type(4)));

#define D_MODEL 2048
#define NH 16
#define HD 128
#define B_ 4
#define T_ 2048
#define M_ (B_*T_)

__device__ __forceinline__ float b2f(ushort_t u){ union{uint32_t i; float f;} v; v.i=((uint32_t)u)<<16; return v.f; }
__device__ __forceinline__ ushort_t f2b(float f){ union{float f; uint32_t i;} v; v.f=f; uint32_t r = v.i + 0x7FFFu + ((v.i>>16)&1u); return (ushort_t)(r>>16); }
__device__ __forceinline__ float fexp2(float x){ return __builtin_amdgcn_exp2f(x); }
__device__ __forceinline__ uint32_t cvtpk(float lo, float hi){
  uint32_t r; asm("v_cvt_pk_bf16_f32 %0, %1, %2" : "=v"(r) : "v"(lo), "v"(hi)); return r;
}
__device__ __forceinline__ uint32_t lswap(uint32_t x){
  asm volatile("v_permlane32_swap_b32 %0, %0" : "+v"(x)); return x;
}

__device__ __forceinline__ void gload16(const void* g, void* l) {
  __builtin_amdgcn_global_load_lds((const __attribute__((address_space(1))) void*)g,
                                   (__attribute__((address_space(3))) void*)l, 16, 0, 0);
}

// ---------------- fused prelude: convert x, transpose W_attn, transpose W_proj, RoPE tables ---
__global__ void prelude_kernel(const float* __restrict__ x, ushort_t* __restrict__ xb,
                               const float* __restrict__ W_attn, ushort_t* __restrict__ Wa,
                               const float* __restrict__ W_proj, ushort_t* __restrict__ Wp,
                               float* __restrict__ cosT, float* __restrict__ sinT) {
  __shared__ float tile[32][33];
  const int b = blockIdx.x, tid = threadIdx.x;
  if (b < 16384) {
    int idx = b*256 + tid;
    float4v v = *reinterpret_cast<const float4v*>(x + (size_t)idx*4);
    ushort4v r;
    #pragma unroll
    for (int e=0;e<4;e++) r[e]=f2b(v[e]);
    *reinterpret_cast<ushort4v*>(xb + (size_t)idx*4) = r;
  } else if (b < 16384 + 12288 + 4096) {
    const bool isA = (b < 16384 + 12288);
    const int r = isA ? (b - 16384) : (b - 16384 - 12288);
    const int NW = isA ? 3*D_MODEL : D_MODEL;
    const int nt = isA ? (r % 192) : (r % 64);
    const int kt = isA ? (r / 192) : (r / 64);
    const float* W = isA ? W_attn : W_proj;
    ushort_t* Wt = isA ? Wa : Wp;
    const int xq = tid & 31, yq = tid >> 5;
    #pragma unroll
    for (int i=0;i<4;i++) {
      int k = kt*32 + yq + i*8;
      tile[yq+i*8][xq] = W[(size_t)k*NW + nt*32 + xq];
    }
    __syncthreads();
    #pragma unroll
    for (int i=0;i<4;i++) {
      int n = nt*32 + yq + i*8;
      Wt[(size_t)n*D_MODEL + kt*32 + xq] = f2b(tile[xq][yq+i*8]);
    }
  } else {
    int idx = (b - 16384 - 12288 - 4096)*256 + tid;
    int t = idx >> 6, i = idx & 63;
    float f = powf(10000.0f, -(float)(2*i)/128.0f);
    float ang = (float)t * f;
    cosT[idx] = cosf(ang);
    sinT[idx] = sinf(ang);
  }
}

// ---------------- GEMM: 128x128 tile, BK=64, 4 waves, SINGLE-buffered LDS (m97 structure) ----
// 32KB LDS -> 5 blocks/CU; barrier drain hidden by inter-block TLP (m114/m99-100 lesson).
// NOTE: no XCD swizzle (R10); no 256²/4-phase (R5/R6/R13 regressed).
template<int EPI>
__global__ __launch_bounds__(256, 2)
void gemm_kernel(const ushort_t* __restrict__ A, const ushort_t* __restrict__ Bt,
                 const float* __restrict__ bias, float* __restrict__ Cf,
                 ushort_t* __restrict__ Qb, ushort_t* __restrict__ Kb, ushort_t* __restrict__ Vb,
                 const float* __restrict__ cosT, const float* __restrict__ sinT,
                 int M, int N, int K) {
  __shared__ __align__(16) ushort_t As[128*64];   // 16KB
  __shared__ __align__(16) ushort_t Bs[128*64];   // 16KB
  const int tid = threadIdx.x, lane = tid & 63, wid = tid >> 6;
  const int bm = blockIdx.x, bn = blockIdx.y;
  const int nt = K >> 6;
  constexpr int MF = (EPI==2) ? 2 : 4;
  constexpr int NF = (EPI==2) ? 8 : 4;
  const int rbase_w = (EPI==2) ? wid*32 : (wid>>1)*64;
  const int cbase_w = (EPI==2) ? 0      : (wid&1)*64;

  f32x4 acc[MF][NF];
  #pragma unroll
  for (int m=0;m<MF;m++)
    #pragma unroll
    for (int n=0;n<NF;n++) { f32x4 z = {0.f,0.f,0.f,0.f}; acc[m][n] = z; }

  const ushort_t* Abase = A + (size_t)(bm*128)*K;
  const ushort_t* Bbase = Bt + (size_t)(bn*128)*K;

  auto stage = [&](int kt) {
    const int rsub = (lane>>3);
    const int g = lane & 7;
    #pragma unroll
    for (int i=0;i<4;i++) {
      int chunk = wid*4 + i;
      int row = chunk*8 + rsub;
      int gl = g ^ (row & 7);
      gload16(Abase + (size_t)row*K + kt*64 + gl*8, &As[chunk*512 + lane*8]);
      gload16(Bbase + (size_t)row*K + kt*64 + gl*8, &Bs[chunk*512 + lane*8]);
    }
  };

  for (int kt=0; kt<nt; ++kt) {
    stage(kt);
    __syncthreads();
    #pragma unroll
    for (int ks=0; ks<2; ++ks) {
      bf16x8 a[MF], b[NF];
      #pragma unroll
      for (int m=0;m<MF;m++) {
        int r = rbase_w + m*16 + (lane&15);
        int gr = (ks*4 + (lane>>4)) ^ (r&7);
        a[m] = *reinterpret_cast<const bf16x8*>(&As[r*64 + gr*8]);
      }
      #pragma unroll
      for (int n=0;n<NF;n++) {
        int r = cbase_w + n*16 + (lane&15);
        int gr = (ks*4 + (lane>>4)) ^ (r&7);
        b[n] = *reinterpret_cast<const bf16x8*>(&Bs[r*64 + gr*8]);
      }
      #pragma unroll
      for (int m=0;m<MF;m++)
        #pragma unroll
        for (int n=0;n<NF;n++)
          acc[m][n] = __builtin_amdgcn_mfma_f32_16x16x32_bf16(a[m], b[n], acc[m][n], 0,0,0);
    }
    __syncthreads();
  }

  if (EPI == 1) {
    #pragma unroll
    for (int m=0;m<MF;m++)
      #pragma unroll
      for (int j=0;j<4;j++) {
        int row = bm*128 + rbase_w + m*16 + (lane>>4)*4 + j;
        #pragma unroll
        for (int n=0;n<NF;n++) {
          int col = bn*128 + cbase_w + n*16 + (lane&15);
          Cf[(size_t)row*N + col] = acc[m][n][j] + bias[col];
        }
      }
  } else {
    const int which = bn >> 4;                // 0=Q, 1=K, 2=V
    const int h = bn & 15;
    if (which < 2) {
      ushort_t* dst = (which==0) ? Qb : Kb;
      #pragma unroll
      for (int m=0;m<MF;m++)
        #pragma unroll
        for (int j=0;j<4;j++) {
          int t = bm*128 + rbase_w + m*16 + (lane>>4)*4 + j;
          int tt = t & (T_-1), bb = t >> 11;
          ushort_t* ptr = dst + ((size_t)(bb*NH + h)*T_ + tt)*HD;
          const float* cb = cosT + tt*64;
          const float* sb = sinT + tt*64;
          #pragma unroll
          for (int n=0;n<4;n++) {
            int d = n*16 + (lane&15);
            float x1 = acc[m][n][j]   + bias[bn*128 + d];
            float x2 = acc[m][n+4][j] + bias[bn*128 + d + 64];
            float cd = cb[d], sd = sb[d];
            ptr[d]    = f2b(x1*cd - x2*sd);
            ptr[d+64] = f2b(x2*cd + x1*sd);
          }
        }
    } else {
      // V: transpose through LDS scratch split across As (d<64) and Bs (d>=64)
      #pragma unroll
      for (int m=0;m<MF;m++)
        #pragma unroll
        for (int j=0;j<4;j++) {
          int r = rbase_w + m*16 + (lane>>4)*4 + j;
          #pragma unroll
          for (int n=0;n<NF;n++) {
            int c = n*16 + (lane&15);
            float v = acc[m][n][j] + bias[bn*128 + c];
            ushort_t* sc = (c & 64) ? &Bs[0] : &As[0];
            sc[(c&63)*128 + (((r>>3)^(c&15))<<3) + (r&7)] = f2b(v);
          }
        }
      __syncthreads();
      int dr = tid >> 1, th = tid & 1;
      const ushort_t* scr = (dr & 64) ? &Bs[0] : &As[0];
      int bb = bm >> 4;
      int t0 = (bm & 15)*128 + th*64;
      ushort_t* dstp = Vb + ((size_t)(bb*NH + h)*HD + dr)*T_ + t0;
      #pragma unroll
      for (int k=0;k<8;k++) {
        ushort8v u = *reinterpret_cast<const ushort8v*>(&scr[(dr&63)*128 + (((th*8+k)^(dr&15))<<3)]);
        *reinterpret_cast<ushort8v*>(dstp + k*8) = u;
      }
    }
  }
}

// ---------------- flash attention (32x32 core, in-register P, V single-buffered) ----------
// Q,K [BH][T][D]; Vt [BH][D][T]; Y [B,T,C] bf16. QBLK=128 (4 waves x 32 q-rows), KVBLK=64.
// K dbuf + V single buffer: LDS 48KB -> 3 blocks/CU. 1D grid, GLOBAL heavy-first order.
__global__ __launch_bounds__(256, 2)
void attn_kernel(const ushort_t* __restrict__ Q, const ushort_t* __restrict__ K,
                 const ushort_t* __restrict__ Vt, ushort_t* __restrict__ Y) {
  __shared__ __align__(16) ushort_t Ks[2][64*128];   // 32KB dbuf
  __shared__ __align__(16) ushort_t Vs[64*128];      // 16KB single (row j = d>>1)
  const int tid = threadIdx.x, lane = tid & 63, w = tid >> 6;
  const int ql = lane & 31, hh = lane >> 5;
  const int id = blockIdx.x;
  const int qtb = 15 - (id >> 6);                    // global heavy-first
  const int bh = id & 63;
  const size_t base = (size_t)bh * T_ * HD;
  const int NT = 2*qtb + 2;
  const int qmin = qtb*128 + w*32;
  const int qrow = qmin + ql;

  auto stageK = [&](int buf, int kvt) {
    #pragma unroll
    for (int i=0;i<4;i++) {
      int c = i*256 + tid;
      int row = c >> 4, sl = c & 15;
      int g = sl ^ (row & 15);
      gload16(K + base + (size_t)(kvt*64 + row)*HD + g*8, &Ks[buf][c*8]);
    }
  };
  auto stageV = [&](int kvt) {
    #pragma unroll
    for (int i=0;i<4;i++) {
      int c = i*256 + tid;
      int j = c >> 4, sl = c & 15;
      int g = sl ^ (j & 15);
      int d = 2*j + (g >> 3);
      gload16(Vt + base + (size_t)d*T_ + kvt*64 + (g&7)*8, &Vs[c*8]);
    }
  };

  stageK(0, 0);

  bf16x8 qf[8];
  {
    const ushort_t* qp = Q + base + (size_t)qrow*HD + hh*8;
    #pragma unroll
    for (int kb=0; kb<8; ++kb) qf[kb] = *reinterpret_cast<const bf16x8*>(qp + kb*16);
  }

  f32x16 o[4];
  #pragma unroll
  for (int nv=0;nv<4;nv++)
    #pragma unroll
    for (int r=0;r<16;r++) o[nv][r] = 0.f;
  float mi = -1e30f, li = 0.f;
  const float C_ = 0.088388347648318447f * 1.4426950408889634f;
  const float THR = 8.0f / (0.088388347648318447f * 1.4426950408889634f);

  for (int kvt=0; kvt<NT; ++kvt) {
    int cur = kvt & 1;
    bool pf = (kvt+1 < NT);
    stageV(kvt);                                 // into single Vs (readers done: end barrier t-1)
    if (pf) stageK(cur^1, kvt+1);
    // wait K[kvt] (oldest 4): outstanding = V[kvt](4) + K[kvt+1](4 if pf)
    if (pf) asm volatile("s_waitcnt vmcnt(8)" ::: "memory");
    else    asm volatile("s_waitcnt vmcnt(4)" ::: "memory");
    __builtin_amdgcn_sched_barrier(0);
    __builtin_amdgcn_s_barrier();
    __builtin_amdgcn_sched_barrier(0);

    bool active = (kvt*64 <= qmin + 31);   // wave-uniform
    f32x16 s0, s1;
    float p0[16], p1[16];
    if (active) {
      #pragma unroll
      for (int r=0;r<16;r++) { s0[r] = 0.f; s1[r] = 0.f; }
      __builtin_amdgcn_s_setprio(1);
      #pragma unroll
      for (int kb=0;kb<8;kb++) {
        int gl = (kb*2 + hh) ^ (ql & 15);
        bf16x8 kf0 = *reinterpret_cast<const bf16x8*>(&Ks[cur][ql*128 + gl*8]);
        s0 = __builtin_amdgcn_mfma_f32_32x32x16_bf16(kf0, qf[kb], s0, 0,0,0);
        bf16x8 kf1 = *reinterpret_cast<const bf16x8*>(&Ks[cur][(32+ql)*128 + gl*8]);
        s1 = __builtin_amdgcn_mfma_f32_32x32x16_bf16(kf1, qf[kb], s1, 0,0,0);
      }
      __builtin_amdgcn_s_setprio(0);
      bool diag = (kvt*64 + 63 > qmin);
      if (diag) {
        #pragma unroll
        for (int r=0;r<16;r++) {
          int kv0 = kvt*64 + (r&3) + 8*(r>>2) + 4*hh;
          if (kv0 > qrow)      s0[r] = -1e30f;
          if (kv0 + 32 > qrow) s1[r] = -1e30f;
        }
      }
      float pm = fmaxf(s0[0], s1[0]);
      #pragma unroll
      for (int r=1;r<16;r++) pm = fmaxf(pm, fmaxf(s0[r], s1[r]));
      pm = fmaxf(pm, __shfl_xor(pm, 32));
      if (__any(pm > mi + THR)) {
        float mn = fmaxf(mi, pm);
        float alpha = fexp2((mi - mn)*C_);
        mi = mn;
        li *= alpha;
        #pragma unroll
        for (int nv=0;nv<4;nv++)
          #pragma unroll
          for (int r=0;r<16;r++) o[nv][r] *= alpha;
      }
      #pragma unroll
      for (int r=0;r<16;r++) {
        p0[r] = fexp2((s0[r] - mi)*C_);
        p1[r] = fexp2((s1[r] - mi)*C_);
      }
      float rs = p0[0] + p1[0];
      #pragma unroll
      for (int r=1;r<16;r++) rs += p0[r] + p1[r];
      rs += __shfl_xor(rs, 32);
      li += rs;
    }
    // wait V[kvt] (own loads), then barrier so ALL waves' V chunks are in LDS
    if (pf) asm volatile("s_waitcnt vmcnt(4)" ::: "memory");
    else    asm volatile("s_waitcnt vmcnt(0)" ::: "memory");
    __builtin_amdgcn_sched_barrier(0);
    __builtin_amdgcn_s_barrier();
    __builtin_amdgcn_sched_barrier(0);
    if (active) {
      // PV: per-ks2 in-register P fragment (cvt_pk + self-permlane swap + cndmask)
      __builtin_amdgcn_s_setprio(1);
      #pragma unroll
      for (int ks2=0; ks2<4; ++ks2) {
        const int b8 = (ks2&1)*8;
        uint32_t c0 = (ks2<2) ? cvtpk(p0[b8+0], p0[b8+1]) : cvtpk(p1[b8+0], p1[b8+1]);
        uint32_t c1 = (ks2<2) ? cvtpk(p0[b8+2], p0[b8+3]) : cvtpk(p1[b8+2], p1[b8+3]);
        uint32_t c2 = (ks2<2) ? cvtpk(p0[b8+4], p0[b8+5]) : cvtpk(p1[b8+4], p1[b8+5]);
        uint32_t c3 = (ks2<2) ? cvtpk(p0[b8+6], p0[b8+7]) : cvtpk(p1[b8+6], p1[b8+7]);
        uint32_t sw0 = lswap(hh ? c0 : c2);
        uint32_t sw1 = lswap(hh ? c1 : c3);
        u32x4 pw;
        pw[0] = hh ? sw0 : c0;
        pw[1] = hh ? sw1 : c1;
        pw[2] = hh ? c2 : sw0;
        pw[3] = hh ? c3 : sw1;
        bf16x8 pa = __builtin_bit_cast(bf16x8, pw);
        #pragma unroll
        for (int nv=0; nv<4; ++nv) {
          int gv = ((ql&1)*8 + ks2*2 + hh) ^ (ql>>1);
          bf16x8 vf = *reinterpret_cast<const bf16x8*>(&Vs[(nv*16 + (ql>>1))*128 + gv*8]);
          o[nv] = __builtin_amdgcn_mfma_f32_32x32x16_bf16(vf, pa, o[nv], 0,0,0);
        }
      }
      __builtin_amdgcn_s_setprio(0);
    }
    __builtin_amdgcn_s_barrier();            // readers done before next V restage / K stage
    __builtin_amdgcn_sched_barrier(0);
  }

  int bb = bh >> 4, hd = bh & 15;
  float inv = 1.0f / li;
  size_t rowbase = ((size_t)(bb*T_ + qrow))*D_MODEL + hd*HD;
  #pragma unroll
  for (int nv=0;nv<4;nv++) {
    #pragma unroll
    for (int qd=0;qd<4;qd++) {
      ushort4v r;
      #pragma unroll
      for (int i=0;i<4;i++) r[i] = f2b(o[nv][qd*4+i] * inv);
      *reinterpret_cast<ushort4v*>(&Y[rowbase + nv*32 + 8*qd + 4*hh]) = r;
    }
  }
}

extern "C" void kernel_launch(void* const* d_in, const int* in_sizes, int n_in,
                              void* d_out, int out_size, void* d_ws, size_t ws_size,
                              hipStream_t stream) {
  const float* x      = (const float*)d_in[0];
  const float* W_attn = (const float*)d_in[1];
  const float* b_attn = (const float*)d_in[2];
  const float* W_proj = (const float*)d_in[3];
  const float* b_proj = (const float*)d_in[4];
  float* out = (float*)d_out;

  char* ws = (char*)d_ws;
  size_t off = 0;
  ushort_t* xb = (ushort_t*)(ws + off); off += (size_t)M_*D_MODEL*2;        // 33.5MB
  ushort_t* Wa = (ushort_t*)(ws + off); off += (size_t)3*D_MODEL*D_MODEL*2; // 25.2MB
  ushort_t* Wp = (ushort_t*)(ws + off); off += (size_t)D_MODEL*D_MODEL*2;   // 8.4MB
  ushort_t* Qb = (ushort_t*)(ws + off); off += (size_t)M_*D_MODEL*2;        // 33.5MB
  ushort_t* Kb = (ushort_t*)(ws + off); off += (size_t)M_*D_MODEL*2;        // 33.5MB
  ushort_t* Vtg= (ushort_t*)(ws + off); off += (size_t)M_*D_MODEL*2;        // 33.5MB
  float* cosT = (float*)(ws + off); off += (size_t)T_*64*4;                 // 0.5MB
  float* sinT = (float*)(ws + off); off += (size_t)T_*64*4;                 // 0.5MB
  ushort_t* Yatt = xb;  // alias: xb dead after GEMM1

  prelude_kernel<<<16384 + 12288 + 4096 + 512, 256, 0, stream>>>(
      x, xb, W_attn, Wa, W_proj, Wp, cosT, sinT);

  gemm_kernel<2><<<dim3(64,48), 256, 0, stream>>>(xb, Wa, b_attn, nullptr,
                                                  Qb, Kb, Vtg, cosT, sinT, M_, 3*D_MODEL, D_MODEL);
  attn_kernel<<<dim3(1024), 256, 0, stream>>>(Qb, Kb, Vtg, Yatt);
  gemm_kernel<1><<<dim3(64,16), 256, 0, stream>>>(Yatt, Wp, b_proj, out,
                                                  nullptr, nullptr, nullptr, nullptr, nullptr,
                                                  M_, D_MODEL, D_MODEL);
}

// Round 22
// 401.530 us; speedup vs baseline: 1.2630x; 1.0043x over previous
//
#include <hip/hip_runtime.h>
#include <hip/hip_bf16.h>
#include <stdint.h>

typedef __bf16 bf16x8 __attribute__((ext_vector_type(8)));
typedef float f32x4 __attribute__((ext_vector_type(4)));
typedef float f32x16 __attribute__((ext_vector_type(16)));
typedef unsigned short ushort_t;
typedef ushort_t ushort4v __attribute__((ext_vector_type(4)));
typedef ushort_t ushort8v __attribute__((ext_vector_type(8)));
typedef float float4v __attribute__((ext_vector_type(4)));
typedef uint32_t u32x4 __attribute__((ext_vector_type(4)));

#define D_MODEL 2048
#define NH 16
#define HD 128
#define B_ 4
#define T_ 2048
#define M_ (B_*T_)

__device__ __forceinline__ float b2f(ushort_t u){ union{uint32_t i; float f;} v; v.i=((uint32_t)u)<<16; return v.f; }
__device__ __forceinline__ ushort_t f2b(float f){ union{float f; uint32_t i;} v; v.f=f; uint32_t r = v.i + 0x7FFFu + ((v.i>>16)&1u); return (ushort_t)(r>>16); }
__device__ __forceinline__ float fexp2(float x){ return __builtin_amdgcn_exp2f(x); }
__device__ __forceinline__ uint32_t cvtpk(float lo, float hi){
  uint32_t r; asm("v_cvt_pk_bf16_f32 %0, %1, %2" : "=v"(r) : "v"(lo), "v"(hi)); return r;
}
__device__ __forceinline__ uint32_t lswap(uint32_t x){
  asm volatile("v_permlane32_swap_b32 %0, %0" : "+v"(x)); return x;
}

__device__ __forceinline__ void gload16(const void* g, void* l) {
  __builtin_amdgcn_global_load_lds((const __attribute__((address_space(1))) void*)g,
                                   (__attribute__((address_space(3))) void*)l, 16, 0, 0);
}

// ---------------- fused prelude: convert x, transpose W_attn, transpose W_proj, RoPE tables ---
__global__ void prelude_kernel(const float* __restrict__ x, ushort_t* __restrict__ xb,
                               const float* __restrict__ W_attn, ushort_t* __restrict__ Wa,
                               const float* __restrict__ W_proj, ushort_t* __restrict__ Wp,
                               float* __restrict__ cosT, float* __restrict__ sinT) {
  __shared__ float tile[32][33];
  const int b = blockIdx.x, tid = threadIdx.x;
  if (b < 16384) {
    int idx = b*256 + tid;
    float4v v = *reinterpret_cast<const float4v*>(x + (size_t)idx*4);
    ushort4v r;
    #pragma unroll
    for (int e=0;e<4;e++) r[e]=f2b(v[e]);
    *reinterpret_cast<ushort4v*>(xb + (size_t)idx*4) = r;
  } else if (b < 16384 + 12288 + 4096) {
    const bool isA = (b < 16384 + 12288);
    const int r = isA ? (b - 16384) : (b - 16384 - 12288);
    const int NW = isA ? 3*D_MODEL : D_MODEL;
    const int nt = isA ? (r % 192) : (r % 64);
    const int kt = isA ? (r / 192) : (r / 64);
    const float* W = isA ? W_attn : W_proj;
    ushort_t* Wt = isA ? Wa : Wp;
    const int xq = tid & 31, yq = tid >> 5;
    #pragma unroll
    for (int i=0;i<4;i++) {
      int k = kt*32 + yq + i*8;
      tile[yq+i*8][xq] = W[(size_t)k*NW + nt*32 + xq];
    }
    __syncthreads();
    #pragma unroll
    for (int i=0;i<4;i++) {
      int n = nt*32 + yq + i*8;
      Wt[(size_t)n*D_MODEL + kt*32 + xq] = f2b(tile[xq][yq+i*8]);
    }
  } else {
    int idx = (b - 16384 - 12288 - 4096)*256 + tid;
    int t = idx >> 6, i = idx & 63;
    float f = powf(10000.0f, -(float)(2*i)/128.0f);
    float ang = (float)t * f;
    cosT[idx] = cosf(ang);
    sinT[idx] = sinf(ang);
  }
}

// ---------------- GEMM: 128x128 tile, BK=64, 4 waves, SINGLE-buffered LDS (m97 structure) ----
// 32KB LDS -> 5 blocks/CU; barrier drain hidden by inter-block TLP (m114/m99-100 lesson).
// NOTE: no XCD swizzle (R10); no 256²/4-phase (R5/R6/R13 regressed).
template<int EPI>
__global__ __launch_bounds__(256, 2)
void gemm_kernel(const ushort_t* __restrict__ A, const ushort_t* __restrict__ Bt,
                 const float* __restrict__ bias, float* __restrict__ Cf,
                 ushort_t* __restrict__ Qb, ushort_t* __restrict__ Kb, ushort_t* __restrict__ Vb,
                 const float* __restrict__ cosT, const float* __restrict__ sinT,
                 int M, int N, int K) {
  __shared__ __align__(16) ushort_t As[128*64];   // 16KB
  __shared__ __align__(16) ushort_t Bs[128*64];   // 16KB
  const int tid = threadIdx.x, lane = tid & 63, wid = tid >> 6;
  const int bm = blockIdx.x, bn = blockIdx.y;
  const int nt = K >> 6;
  constexpr int MF = (EPI==2) ? 2 : 4;
  constexpr int NF = (EPI==2) ? 8 : 4;
  const int rbase_w = (EPI==2) ? wid*32 : (wid>>1)*64;
  const int cbase_w = (EPI==2) ? 0      : (wid&1)*64;

  f32x4 acc[MF][NF];
  #pragma unroll
  for (int m=0;m<MF;m++)
    #pragma unroll
    for (int n=0;n<NF;n++) { f32x4 z = {0.f,0.f,0.f,0.f}; acc[m][n] = z; }

  const ushort_t* Abase = A + (size_t)(bm*128)*K;
  const ushort_t* Bbase = Bt + (size_t)(bn*128)*K;

  auto stage = [&](int kt) {
    const int rsub = (lane>>3);
    const int g = lane & 7;
    #pragma unroll
    for (int i=0;i<4;i++) {
      int chunk = wid*4 + i;
      int row = chunk*8 + rsub;
      int gl = g ^ (row & 7);
      gload16(Abase + (size_t)row*K + kt*64 + gl*8, &As[chunk*512 + lane*8]);
      gload16(Bbase + (size_t)row*K + kt*64 + gl*8, &Bs[chunk*512 + lane*8]);
    }
  };

  for (int kt=0; kt<nt; ++kt) {
    stage(kt);
    __syncthreads();
    #pragma unroll
    for (int ks=0; ks<2; ++ks) {
      bf16x8 a[MF], b[NF];
      #pragma unroll
      for (int m=0;m<MF;m++) {
        int r = rbase_w + m*16 + (lane&15);
        int gr = (ks*4 + (lane>>4)) ^ (r&7);
        a[m] = *reinterpret_cast<const bf16x8*>(&As[r*64 + gr*8]);
      }
      #pragma unroll
      for (int n=0;n<NF;n++) {
        int r = cbase_w + n*16 + (lane&15);
        int gr = (ks*4 + (lane>>4)) ^ (r&7);
        b[n] = *reinterpret_cast<const bf16x8*>(&Bs[r*64 + gr*8]);
      }
      #pragma unroll
      for (int m=0;m<MF;m++)
        #pragma unroll
        for (int n=0;n<NF;n++)
          acc[m][n] = __builtin_amdgcn_mfma_f32_16x16x32_bf16(a[m], b[n], acc[m][n], 0,0,0);
    }
    __syncthreads();
  }

  if (EPI == 1) {
    #pragma unroll
    for (int m=0;m<MF;m++)
      #pragma unroll
      for (int j=0;j<4;j++) {
        int row = bm*128 + rbase_w + m*16 + (lane>>4)*4 + j;
        #pragma unroll
        for (int n=0;n<NF;n++) {
          int col = bn*128 + cbase_w + n*16 + (lane&15);
          Cf[(size_t)row*N + col] = acc[m][n][j] + bias[col];
        }
      }
  } else {
    const int which = bn >> 4;                // 0=Q, 1=K, 2=V
    const int h = bn & 15;
    if (which < 2) {
      ushort_t* dst = (which==0) ? Qb : Kb;
      #pragma unroll
      for (int m=0;m<MF;m++)
        #pragma unroll
        for (int j=0;j<4;j++) {
          int t = bm*128 + rbase_w + m*16 + (lane>>4)*4 + j;
          int tt = t & (T_-1), bb = t >> 11;
          ushort_t* ptr = dst + ((size_t)(bb*NH + h)*T_ + tt)*HD;
          const float* cb = cosT + tt*64;
          const float* sb = sinT + tt*64;
          #pragma unroll
          for (int n=0;n<4;n++) {
            int d = n*16 + (lane&15);
            float x1 = acc[m][n][j]   + bias[bn*128 + d];
            float x2 = acc[m][n+4][j] + bias[bn*128 + d + 64];
            float cd = cb[d], sd = sb[d];
            ptr[d]    = f2b(x1*cd - x2*sd);
            ptr[d+64] = f2b(x2*cd + x1*sd);
          }
        }
    } else {
      // V: transpose through LDS scratch split across As (d<64) and Bs (d>=64)
      #pragma unroll
      for (int m=0;m<MF;m++)
        #pragma unroll
        for (int j=0;j<4;j++) {
          int r = rbase_w + m*16 + (lane>>4)*4 + j;
          #pragma unroll
          for (int n=0;n<NF;n++) {
            int c = n*16 + (lane&15);
            float v = acc[m][n][j] + bias[bn*128 + c];
            ushort_t* sc = (c & 64) ? &Bs[0] : &As[0];
            sc[(c&63)*128 + (((r>>3)^(c&15))<<3) + (r&7)] = f2b(v);
          }
        }
      __syncthreads();
      int dr = tid >> 1, th = tid & 1;
      const ushort_t* scr = (dr & 64) ? &Bs[0] : &As[0];
      int bb = bm >> 4;
      int t0 = (bm & 15)*128 + th*64;
      ushort_t* dstp = Vb + ((size_t)(bb*NH + h)*HD + dr)*T_ + t0;
      #pragma unroll
      for (int k=0;k<8;k++) {
        ushort8v u = *reinterpret_cast<const ushort8v*>(&scr[(dr&63)*128 + (((th*8+k)^(dr&15))<<3)]);
        *reinterpret_cast<ushort8v*>(dstp + k*8) = u;
      }
    }
  }
}

// ---------------- flash attention (32x32 core, in-register P, K AND V single-buffered) ----
// Q,K [BH][T][D]; Vt [BH][D][T]; Y [B,T,C] bf16. QBLK=128 (4 waves x 32 q-rows), KVBLK=64.
// LDS 32KB -> 5 blocks/CU (mirror of the R20 GEMM single-buffer win: TLP hides latency).
// Per tile: stageK(t); stageV(t); vmcnt(4) barrier; QK^T+softmax; vmcnt(0) barrier; PV; end barrier.
// 1D grid, GLOBAL heavy-first order.
__global__ __launch_bounds__(256, 2)
void attn_kernel(const ushort_t* __restrict__ Q, const ushort_t* __restrict__ K,
                 const ushort_t* __restrict__ Vt, ushort_t* __restrict__ Y) {
  __shared__ __align__(16) ushort_t Ks[64*128];      // 16KB single
  __shared__ __align__(16) ushort_t Vs[64*128];      // 16KB single (row j = d>>1)
  const int tid = threadIdx.x, lane = tid & 63, w = tid >> 6;
  const int ql = lane & 31, hh = lane >> 5;
  const int id = blockIdx.x;
  const int qtb = 15 - (id >> 6);                    // global heavy-first
  const int bh = id & 63;
  const size_t base = (size_t)bh * T_ * HD;
  const int NT = 2*qtb + 2;
  const int qmin = qtb*128 + w*32;
  const int qrow = qmin + ql;

  auto stageK = [&](int kvt) {
    #pragma unroll
    for (int i=0;i<4;i++) {
      int c = i*256 + tid;
      int row = c >> 4, sl = c & 15;
      int g = sl ^ (row & 15);
      gload16(K + base + (size_t)(kvt*64 + row)*HD + g*8, &Ks[c*8]);
    }
  };
  auto stageV = [&](int kvt) {
    #pragma unroll
    for (int i=0;i<4;i++) {
      int c = i*256 + tid;
      int j = c >> 4, sl = c & 15;
      int g = sl ^ (j & 15);
      int d = 2*j + (g >> 3);
      gload16(Vt + base + (size_t)d*T_ + kvt*64 + (g&7)*8, &Vs[c*8]);
    }
  };

  bf16x8 qf[8];
  {
    const ushort_t* qp = Q + base + (size_t)qrow*HD + hh*8;
    #pragma unroll
    for (int kb=0; kb<8; ++kb) qf[kb] = *reinterpret_cast<const bf16x8*>(qp + kb*16);
  }

  f32x16 o[4];
  #pragma unroll
  for (int nv=0;nv<4;nv++)
    #pragma unroll
    for (int r=0;r<16;r++) o[nv][r] = 0.f;
  float mi = -1e30f, li = 0.f;
  const float C_ = 0.088388347648318447f * 1.4426950408889634f;
  const float THR = 8.0f / (0.088388347648318447f * 1.4426950408889634f);

  for (int kvt=0; kvt<NT; ++kvt) {
    stageK(kvt);                                // readers of tile t-1 done (end barrier)
    stageV(kvt);
    asm volatile("s_waitcnt vmcnt(4)" ::: "memory");   // K's 4 (oldest) landed
    __builtin_amdgcn_sched_barrier(0);
    __builtin_amdgcn_s_barrier();
    __builtin_amdgcn_sched_barrier(0);

    bool active = (kvt*64 <= qmin + 31);   // wave-uniform
    f32x16 s0, s1;
    float p0[16], p1[16];
    if (active) {
      #pragma unroll
      for (int r=0;r<16;r++) { s0[r] = 0.f; s1[r] = 0.f; }
      __builtin_amdgcn_s_setprio(1);
      #pragma unroll
      for (int kb=0;kb<8;kb++) {
        int gl = (kb*2 + hh) ^ (ql & 15);
        bf16x8 kf0 = *reinterpret_cast<const bf16x8*>(&Ks[ql*128 + gl*8]);
        s0 = __builtin_amdgcn_mfma_f32_32x32x16_bf16(kf0, qf[kb], s0, 0,0,0);
        bf16x8 kf1 = *reinterpret_cast<const bf16x8*>(&Ks[(32+ql)*128 + gl*8]);
        s1 = __builtin_amdgcn_mfma_f32_32x32x16_bf16(kf1, qf[kb], s1, 0,0,0);
      }
      __builtin_amdgcn_s_setprio(0);
      bool diag = (kvt*64 + 63 > qmin);
      if (diag) {
        #pragma unroll
        for (int r=0;r<16;r++) {
          int kv0 = kvt*64 + (r&3) + 8*(r>>2) + 4*hh;
          if (kv0 > qrow)      s0[r] = -1e30f;
          if (kv0 + 32 > qrow) s1[r] = -1e30f;
        }
      }
      float pm = fmaxf(s0[0], s1[0]);
      #pragma unroll
      for (int r=1;r<16;r++) pm = fmaxf(pm, fmaxf(s0[r], s1[r]));
      pm = fmaxf(pm, __shfl_xor(pm, 32));
      if (__any(pm > mi + THR)) {
        float mn = fmaxf(mi, pm);
        float alpha = fexp2((mi - mn)*C_);
        mi = mn;
        li *= alpha;
        #pragma unroll
        for (int nv=0;nv<4;nv++)
          #pragma unroll
          for (int r=0;r<16;r++) o[nv][r] *= alpha;
      }
      #pragma unroll
      for (int r=0;r<16;r++) {
        p0[r] = fexp2((s0[r] - mi)*C_);
        p1[r] = fexp2((s1[r] - mi)*C_);
      }
      float rs = p0[0] + p1[0];
      #pragma unroll
      for (int r=1;r<16;r++) rs += p0[r] + p1[r];
      rs += __shfl_xor(rs, 32);
      li += rs;
    }
    // wait V[kvt], then barrier so ALL waves' V chunks are in LDS
    asm volatile("s_waitcnt vmcnt(0)" ::: "memory");
    __builtin_amdgcn_sched_barrier(0);
    __builtin_amdgcn_s_barrier();
    __builtin_amdgcn_sched_barrier(0);
    if (active) {
      // PV: per-ks2 in-register P fragment (cvt_pk + self-permlane swap + cndmask)
      __builtin_amdgcn_s_setprio(1);
      #pragma unroll
      for (int ks2=0; ks2<4; ++ks2) {
        const int b8 = (ks2&1)*8;
        uint32_t c0 = (ks2<2) ? cvtpk(p0[b8+0], p0[b8+1]) : cvtpk(p1[b8+0], p1[b8+1]);
        uint32_t c1 = (ks2<2) ? cvtpk(p0[b8+2], p0[b8+3]) : cvtpk(p1[b8+2], p1[b8+3]);
        uint32_t c2 = (ks2<2) ? cvtpk(p0[b8+4], p0[b8+5]) : cvtpk(p1[b8+4], p1[b8+5]);
        uint32_t c3 = (ks2<2) ? cvtpk(p0[b8+6], p0[b8+7]) : cvtpk(p1[b8+6], p1[b8+7]);
        uint32_t sw0 = lswap(hh ? c0 : c2);
        uint32_t sw1 = lswap(hh ? c1 : c3);
        u32x4 pw;
        pw[0] = hh ? sw0 : c0;
        pw[1] = hh ? sw1 : c1;
        pw[2] = hh ? c2 : sw0;
        pw[3] = hh ? c3 : sw1;
        bf16x8 pa = __builtin_bit_cast(bf16x8, pw);
        #pragma unroll
        for (int nv=0; nv<4; ++nv) {
          int gv = ((ql&1)*8 + ks2*2 + hh) ^ (ql>>1);
          bf16x8 vf = *reinterpret_cast<const bf16x8*>(&Vs[(nv*16 + (ql>>1))*128 + gv*8]);
          o[nv] = __builtin_amdgcn_mfma_f32_32x32x16_bf16(vf, pa, o[nv], 0,0,0);
        }
      }
      __builtin_amdgcn_s_setprio(0);
    }
    __builtin_amdgcn_s_barrier();            // readers done before next K/V restage
    __builtin_amdgcn_sched_barrier(0);
  }

  int bb = bh >> 4, hd = bh & 15;
  float inv = 1.0f / li;
  size_t rowbase = ((size_t)(bb*T_ + qrow))*D_MODEL + hd*HD;
  #pragma unroll
  for (int nv=0;nv<4;nv++) {
    #pragma unroll
    for (int qd=0;qd<4;qd++) {
      ushort4v r;
      #pragma unroll
      for (int i=0;i<4;i++) r[i] = f2b(o[nv][qd*4+i] * inv);
      *reinterpret_cast<ushort4v*>(&Y[rowbase + nv*32 + 8*qd + 4*hh]) = r;
    }
  }
}

extern "C" void kernel_launch(void* const* d_in, const int* in_sizes, int n_in,
                              void* d_out, int out_size, void* d_ws, size_t ws_size,
                              hipStream_t stream) {
  const float* x      = (const float*)d_in[0];
  const float* W_attn = (const float*)d_in[1];
  const float* b_attn = (const float*)d_in[2];
  const float* W_proj = (const float*)d_in[3];
  const float* b_proj = (const float*)d_in[4];
  float* out = (float*)d_out;

  char* ws = (char*)d_ws;
  size_t off = 0;
  ushort_t* xb = (ushort_t*)(ws + off); off += (size_t)M_*D_MODEL*2;        // 33.5MB
  ushort_t* Wa = (ushort_t*)(ws + off); off += (size_t)3*D_MODEL*D_MODEL*2; // 25.2MB
  ushort_t* Wp = (ushort_t*)(ws + off); off += (size_t)D_MODEL*D_MODEL*2;   // 8.4MB
  ushort_t* Qb = (ushort_t*)(ws + off); off += (size_t)M_*D_MODEL*2;        // 33.5MB
  ushort_t* Kb = (ushort_t*)(ws + off); off += (size_t)M_*D_MODEL*2;        // 33.5MB
  ushort_t* Vtg= (ushort_t*)(ws + off); off += (size_t)M_*D_MODEL*2;        // 33.5MB
  float* cosT = (float*)(ws + off); off += (size_t)T_*64*4;                 // 0.5MB
  float* sinT = (float*)(ws + off); off += (size_t)T_*64*4;                 // 0.5MB
  ushort_t* Yatt = xb;  // alias: xb dead after GEMM1

  prelude_kernel<<<16384 + 12288 + 4096 + 512, 256, 0, stream>>>(
      x, xb, W_attn, Wa, W_proj, Wp, cosT, sinT);

  gemm_kernel<2><<<dim3(64,48), 256, 0, stream>>>(xb, Wa, b_attn, nullptr,
                                                  Qb, Kb, Vtg, cosT, sinT, M_, 3*D_MODEL, D_MODEL);
  attn_kernel<<<dim3(1024), 256, 0, stream>>>(Qb, Kb, Vtg, Yatt);
  gemm_kernel<1><<<dim3(64,16), 256, 0, stream>>>(Yatt, Wp, b_proj, out,
                                                  nullptr, nullptr, nullptr, nullptr, nullptr,
                                                  M_, D_MODEL, D_MODEL);
}